// Round 8
// baseline (375.233 us; speedup 1.0000x reference)
//
#include <hip/hip_runtime.h>
#include <stdint.h>

// Problem sizes.
static constexpr int Bn = 4096;
static constexpr int Dn = 5000;
static constexpr int Hn = 2000;
static constexpr int Ln = 50;
static constexpr int XW = 80;      // u64 words covering D (5120 bits >= 5000)
static constexpr int Hpad = 2048;  // padded H bit capacity (64 u32 words)
static constexpr int Dpad = 5120;  // padded D = XW*64

__device__ __forceinline__ int popc_acc(uint64_t v, int acc) {
  // 2x v_and_b32 + 2x v_bcnt_u32_b32 (fused accumulate)
  acc = __builtin_popcount((uint32_t)v) + acc;
  acc = __builtin_popcount((uint32_t)(v >> 32)) + acc;
  return acc;
}

// Pack x rows into word-PAIRED transposed bit matrix xb2[w2][b][2] (ulong2) so the
// encoder loads 16B per 2 K-words. 4 words/wave, coalesced reads.
__global__ void k_pack_x(const float* __restrict__ x, uint64_t* __restrict__ xb2) {
  int g = (int)((blockIdx.x * blockDim.x + threadIdx.x) >> 6);
  int lane = (int)(threadIdx.x & 63);
  constexpr int nq = XW >> 2;  // 20
  int row = g / nq;
  int q = g - row * nq;
  if (row >= Bn) return;
  int w0 = q << 2;
  unsigned long long m[4];
#pragma unroll
  for (int e = 0; e < 4; ++e) {
    int col = ((w0 + e) << 6) + lane;
    float v = (col < Dn) ? x[(size_t)row * Dn + col] : 0.0f;
    m[e] = __ballot(v >= 0.5f);
  }
  if (lane < 4) {
    unsigned long long mv = m[0];
    mv = (lane == 1) ? m[1] : mv;
    mv = (lane == 2) ? m[2] : mv;
    mv = (lane == 3) ? m[3] : mv;
    int w = w0 + lane;
    xb2[((size_t)(w >> 1) * Bn + row) * 2 + (w & 1)] = mv;  // [XW/2][Bn][2]
  }
}

// One coalesced pass over W -> transposed row bitsets wbT[w][j] (u64, ballot over
// d-lanes) AND transposed column bitsets wt32[hw][d] (u32 over 32 j-rows each,
// per-thread bit accumulation, coalesced store). Padding comes out zero.
__global__ __launch_bounds__(256) void k_pack_w(const float* __restrict__ W,
                                                uint64_t* __restrict__ wbT,
                                                uint32_t* __restrict__ wt32) {
  int d = (int)blockIdx.x * 256 + (int)threadIdx.x;  // 0..5119
  int j0 = (int)blockIdx.y * 64;                     // 32 blocks of 64 j
  int lane = (int)(threadIdx.x & 63);
  int wv = (int)(threadIdx.x >> 6);                  // d-word sub-index in block
  uint64_t colbits = 0;
  for (int r = 0; r < 64; ++r) {
    int j = j0 + r;
    float v = (j < Hn && d < Dn) ? W[(size_t)j * Dn + d] : 0.0f;
    bool bit = v >= 0.5f;
    colbits |= ((uint64_t)(bit ? 1u : 0u)) << r;
    unsigned long long m = __ballot(bit);
    if (lane == 0) wbT[(size_t)(blockIdx.x * 4 + wv) * Hpad + j] = m;
  }
  wt32[(size_t)(blockIdx.y * 2) * Dpad + d] = (uint32_t)colbits;
  wt32[(size_t)(blockIdx.y * 2 + 1) * Dpad + d] = (uint32_t)(colbits >> 32);
}

// fwT[j][l] = sigmoid(2 * cw[l][j]), padded to 64 cols (pad = 0).
__global__ void k_pack_fwT(const float* __restrict__ cw, float* __restrict__ fwT) {
  int idx = blockIdx.x * blockDim.x + threadIdx.x;
  if (idx >= Hn * 64) return;
  int j = idx >> 6, l = idx & 63;
  float v = 0.0f;
  if (l < Ln) {
    float t = 2.0f * cw[(size_t)l * Hn + j];
    v = 1.0f / (1.0f + expf(-t));
  }
  fwT[idx] = v;
}

__global__ void k_zero(float* __restrict__ p, int n) {
  int i = blockIdx.x * blockDim.x + threadIdx.x;
  if (i < n) p[i] = 0.0f;
}

// Encoder: wave = 256 batch rows (4 per lane) x 8 hidden units.
// Per w2-iter: 4 coalesced dwordx4 x-loads + 8 broadcast ds_read_b128 + 256 VALU
// popcount insts (VALU:DS = 32:1). Each LDS weight read feeds 4 MACs per lane.
__global__ __launch_bounds__(256) void k_enc(const uint64_t* __restrict__ xb2,
                                             const uint64_t* __restrict__ wbT,
                                             const float* __restrict__ b_enc,
                                             const float* __restrict__ act0b,
                                             float* __restrict__ z_out,
                                             uint8_t* __restrict__ zb8) {
  __shared__ uint64_t wl[XW][8];  // 5120 B
  int tid = (int)threadIdx.x;
  int jg = (int)blockIdx.x;  // 0..255: j-group of 8
  int j0 = jg << 3;
#pragma unroll
  for (int k = 0; k < 3; ++k) {
    int idx = k * 256 + tid;
    if (idx < XW * 8) {
      int w = idx >> 3, j = idx & 7;
      wl[w][j] = wbT[(size_t)w * Hpad + j0 + j];
    }
  }
  __syncthreads();

  int wv = __builtin_amdgcn_readfirstlane(tid >> 6);
  int lane = tid & 63;
  int bg = (int)blockIdx.y * 4 + wv;  // 0..15: batch group of 256
  int b0 = (bg << 8) + lane;

  int acc[4][8] = {};
  const uint64_t* xp = xb2 + 2 * (size_t)b0;
#pragma unroll 1
  for (int w2 = 0; w2 < XW / 2; ++w2) {
    ulong2 xx[4];
#pragma unroll
    for (int i = 0; i < 4; ++i)
      xx[i] = *(const ulong2*)(xp + ((size_t)w2 * Bn + i * 64) * 2);
#pragma unroll
    for (int t2 = 0; t2 < 4; ++t2) {
      ulong2 wa = *(ulong2*)&wl[2 * w2][2 * t2];      // broadcast ds_read_b128
      ulong2 wb = *(ulong2*)&wl[2 * w2 + 1][2 * t2];  // broadcast ds_read_b128
#pragma unroll
      for (int i = 0; i < 4; ++i) {
        acc[i][2 * t2]     = popc_acc(xx[i].x & wa.x, acc[i][2 * t2]);
        acc[i][2 * t2 + 1] = popc_acc(xx[i].x & wa.y, acc[i][2 * t2 + 1]);
        acc[i][2 * t2]     = popc_acc(xx[i].y & wb.x, acc[i][2 * t2]);
        acc[i][2 * t2 + 1] = popc_acc(xx[i].y & wb.y, acc[i][2 * t2 + 1]);
      }
    }
  }

  float be[8], ab[8];
#pragma unroll
  for (int t = 0; t < 8; ++t) {
    int j = j0 + t;
    int js = (j < Hn) ? j : (Hn - 1);
    be[t] = b_enc[js];
    ab[t] = act0b[js];
  }
#pragma unroll
  for (int i = 0; i < 4; ++i) {
    int b = b0 + i * 64;
    uint32_t zbyte = 0;
    float zf[8];
#pragma unroll
    for (int t = 0; t < 8; ++t) {
      int j = j0 + t;
      // exact: integer-valued acc + b_enc, then + act0_bias (reference order)
      float h = ((float)acc[i][t] + be[t]) + ab[t];
      bool zb = (j < Hn) && (h >= 1.0f);
      zbyte |= zb ? (1u << t) : 0u;
      zf[t] = zb ? 1.0f : 0.0f;
    }
    // byte (jg&3) of u32 word hw = jg>>2 in [hw][Bn] layout (little-endian match)
    zb8[((size_t)(jg >> 2) * Bn + b) * 4 + (jg & 3)] = (uint8_t)zbyte;
    if (j0 < Hn) {  // 2000 % 8 == 0: group fully valid or fully padded
      float* zp = z_out + (size_t)b * Hn + j0;
      *(float4*)zp = make_float4(zf[0], zf[1], zf[2], zf[3]);
      *(float4*)(zp + 4) = make_float4(zf[4], zf[5], zf[6], zf[7]);
    }
  }
}

// Decoder: wave = 256 batch rows (4 per lane) x 16 outputs.
// Per hw-iter: 4 coalesced z-word loads + 4 broadcast ds_read_b128 + 128 VALU
// popcount insts (VALU:DS = 32:1).
__global__ __launch_bounds__(256) void k_dec(const uint32_t* __restrict__ zb32,
                                             const uint32_t* __restrict__ wt32,
                                             const float* __restrict__ act3b,
                                             float* __restrict__ out) {
  __shared__ uint32_t tl[64][16];  // 4096 B
  int tid = (int)threadIdx.x;
  int dc = (int)blockIdx.x;  // 0..319: d-chunk of 16
  int d0 = dc << 4;
#pragma unroll
  for (int k = 0; k < 4; ++k) {
    int idx = k * 256 + tid;  // 0..1023
    int hw = idx >> 4, dl = idx & 15;
    tl[hw][dl] = wt32[(size_t)hw * Dpad + d0 + dl];
  }
  __syncthreads();

  int wv = __builtin_amdgcn_readfirstlane(tid >> 6);
  int lane = tid & 63;
  int bg = (int)blockIdx.y * 4 + wv;  // 0..15
  int b0 = (bg << 8) + lane;

  int acc[4][16] = {};
  const uint32_t* zp = zb32 + b0;
#pragma unroll 2
  for (int hw = 0; hw < 64; ++hw) {
    uint32_t zw[4];
#pragma unroll
    for (int i = 0; i < 4; ++i) zw[i] = zp[(size_t)hw * Bn + i * 64];
#pragma unroll
    for (int q = 0; q < 4; ++q) {
      uint4 w4 = *(uint4*)&tl[hw][q * 4];  // broadcast ds_read_b128
#pragma unroll
      for (int i = 0; i < 4; ++i) {
        acc[i][4 * q]     = __builtin_popcount(zw[i] & w4.x) + acc[i][4 * q];
        acc[i][4 * q + 1] = __builtin_popcount(zw[i] & w4.y) + acc[i][4 * q + 1];
        acc[i][4 * q + 2] = __builtin_popcount(zw[i] & w4.z) + acc[i][4 * q + 2];
        acc[i][4 * q + 3] = __builtin_popcount(zw[i] & w4.w) + acc[i][4 * q + 3];
      }
    }
  }

  float ab[16];
#pragma unroll
  for (int t = 0; t < 16; ++t) {
    int d = d0 + t;
    int ds = (d < Dn) ? d : (Dn - 1);
    ab[t] = act3b[ds];
  }
#pragma unroll
  for (int i = 0; i < 4; ++i) {
    int b = b0 + i * 64;
    float of[16];
#pragma unroll
    for (int t = 0; t < 16; ++t)
      of[t] = (((float)acc[i][t] + ab[t]) >= 1.0f) ? 1.0f : 0.0f;
    float* op = out + (size_t)b * Dn + d0;
#pragma unroll
    for (int q = 0; q < 4; ++q)
      if (d0 + 4 * q < Dn)  // uniform; 5000 % 4 == 0
        *(float4*)(op + 4 * q) =
            make_float4(of[4 * q], of[4 * q + 1], of[4 * q + 2], of[4 * q + 3]);
  }
}

// classification = z @ fwT: LDS-tiled outer-product GEMM.
// Block = 128 b-rows x 64 l x 256 j-slice (4 tiles of 64 j). Thread = 8b x 4l.
__global__ __launch_bounds__(256) void k_cls(const float* __restrict__ z,
                                             const float* __restrict__ fwT,
                                             float* __restrict__ cls) {
  __shared__ float zT[64][132];   // transposed z tile, padded stride
  __shared__ float fwL[64][64];   // fw tile
  int tid = (int)threadIdx.x;
  int bb0 = (int)blockIdx.x * 128;
  int jsp = (int)blockIdx.y;      // 0..7
  int tx = tid & 15, ty = tid >> 4;
  float acc[8][4] = {};

  for (int tile = 0; tile < 4; ++tile) {
    int jt0 = jsp * 256 + tile * 64;
    __syncthreads();
#pragma unroll
    for (int k = 0; k < 8; ++k) {
      int idx = k * 256 + tid;
      int r = idx >> 4, c4 = idx & 15;
      int j = jt0 + c4 * 4;
      float4 v = make_float4(0.f, 0.f, 0.f, 0.f);
      if (j < Hn) v = *(const float4*)(z + (size_t)(bb0 + r) * Hn + j);
      zT[c4 * 4 + 0][r] = v.x;
      zT[c4 * 4 + 1][r] = v.y;
      zT[c4 * 4 + 2][r] = v.z;
      zT[c4 * 4 + 3][r] = v.w;
    }
#pragma unroll
    for (int k = 0; k < 4; ++k) {
      int idx = k * 256 + tid;
      int jj = idx >> 4, c4 = idx & 15;
      int j = jt0 + jj;
      float4 v = make_float4(0.f, 0.f, 0.f, 0.f);
      if (j < Hn) v = *(const float4*)(fwT + (size_t)j * 64 + c4 * 4);
      *(float4*)&fwL[jj][c4 * 4] = v;
    }
    __syncthreads();
#pragma unroll 4
    for (int jj = 0; jj < 64; ++jj) {
      float4 fv = *(float4*)&fwL[jj][tx * 4];
      float4 za = *(float4*)&zT[jj][ty * 8];
      float4 zb = *(float4*)&zT[jj][ty * 8 + 4];
      float zz[8] = {za.x, za.y, za.z, za.w, zb.x, zb.y, zb.z, zb.w};
      float ff[4] = {fv.x, fv.y, fv.z, fv.w};
#pragma unroll
      for (int i = 0; i < 8; ++i)
#pragma unroll
        for (int l = 0; l < 4; ++l) acc[i][l] += zz[i] * ff[l];
    }
  }

#pragma unroll
  for (int i = 0; i < 8; ++i) {
    int b = bb0 + ty * 8 + i;
#pragma unroll
    for (int l = 0; l < 4; ++l) {
      int L = tx * 4 + l;
      if (L < Ln) atomicAdd(&cls[(size_t)b * Ln + L], acc[i][l]);
    }
  }
}

extern "C" void kernel_launch(void* const* d_in, const int* in_sizes, int n_in,
                              void* d_out, int out_size, void* d_ws, size_t ws_size,
                              hipStream_t stream) {
  const float* x     = (const float*)d_in[0];  // [B][D]
  const float* W     = (const float*)d_in[1];  // [H][D]
  const float* b_enc = (const float*)d_in[2];  // [H]
  const float* act0b = (const float*)d_in[3];  // [H]
  const float* act3b = (const float*)d_in[4];  // [D]
  const float* cw    = (const float*)d_in[5];  // [L][H]

  float* out0 = (float*)d_out;              // output        [B][D]
  float* cls  = out0 + (size_t)Bn * Dn;     // classification[B][L]
  float* zout = cls + (size_t)Bn * Ln;      // z             [B][H]

  // Workspace (~6.8 MB).
  char* ws = (char*)d_ws;
  uint64_t* xb2  = (uint64_t*)ws; ws += (size_t)XW * Bn * 8;    // 2.62 MB [40][Bn][2]
  uint64_t* wbT  = (uint64_t*)ws; ws += (size_t)XW * Hpad * 8;  // 1.31 MB [80][Hpad]
  uint32_t* wt32 = (uint32_t*)ws; ws += (size_t)64 * Dpad * 4;  // 1.31 MB [64][Dpad]
  uint32_t* zb32 = (uint32_t*)ws; ws += (size_t)64 * Bn * 4;    // 1.05 MB [64][Bn] u32 (byte-assembled)
  float*    fwT  = (float*)ws;    ws += (size_t)Hn * 64 * 4;    // 0.51 MB

  {  // x -> xb2 (paired word-major transpose)
    long long waves = (long long)Bn * (XW / 4);
    k_pack_x<<<(int)((waves * 64 + 255) / 256), 256, 0, stream>>>(x, xb2);
  }
  {  // W -> wbT + wt32 in one coalesced pass
    dim3 gw2(Dpad / 256, Hpad / 64);  // (20, 32)
    k_pack_w<<<gw2, 256, 0, stream>>>(W, wbT, wt32);
  }
  k_pack_fwT<<<(Hn * 64 + 255) / 256, 256, 0, stream>>>(cw, fwT);
  k_zero<<<(Bn * Ln + 255) / 256, 256, 0, stream>>>(cls, Bn * Ln);

  // enc: 256 j-groups x (4 blocks x 4 waves = 16 batch groups) = 4096 waves
  dim3 g1(256, 4);
  k_enc<<<g1, 256, 0, stream>>>(xb2, wbT, b_enc, act0b, zout, (uint8_t*)zb32);

  // cls: 32 b-blocks x 8 j-splits = 256 blocks
  dim3 g3(32, 8);
  k_cls<<<g3, 256, 0, stream>>>(zout, fwT, cls);

  // dec: 320 d-chunks x 16 batch groups = 5120 waves
  dim3 g2(320, 4);
  k_dec<<<g2, 256, 0, stream>>>(zb32, wt32, act3b, out0);
}

// Round 9
// 326.412 us; speedup vs baseline: 1.1496x; 1.1496x over previous
//
#include <hip/hip_runtime.h>
#include <stdint.h>

// Problem sizes.
static constexpr int Bn = 4096;
static constexpr int Dn = 5000;
static constexpr int Hn = 2000;
static constexpr int Ln = 50;
static constexpr int XW = 80;      // u64 words covering D (5120 bits >= 5000)
static constexpr int Hpad = 2048;  // padded H bit capacity (64 u32 words)
static constexpr int Dpad = 5120;  // padded D = XW*64

__device__ __forceinline__ int popc_acc(uint64_t v, int acc) {
  // 2x v_and_b32 + 2x v_bcnt_u32_b32 (fused accumulate)
  acc = __builtin_popcount((uint32_t)v) + acc;
  acc = __builtin_popcount((uint32_t)(v >> 32)) + acc;
  return acc;
}

// Pack x rows into word-PAIRED transposed bit matrix xb2[w2][b][2] (ulong2) so the
// encoder loads 16B per 2 K-words. 4 words/wave, coalesced reads.
__global__ void k_pack_x(const float* __restrict__ x, uint64_t* __restrict__ xb2) {
  int g = (int)((blockIdx.x * blockDim.x + threadIdx.x) >> 6);
  int lane = (int)(threadIdx.x & 63);
  constexpr int nq = XW >> 2;  // 20
  int row = g / nq;
  int q = g - row * nq;
  if (row >= Bn) return;
  int w0 = q << 2;
  unsigned long long m[4];
#pragma unroll
  for (int e = 0; e < 4; ++e) {
    int col = ((w0 + e) << 6) + lane;
    float v = (col < Dn) ? x[(size_t)row * Dn + col] : 0.0f;
    m[e] = __ballot(v >= 0.5f);
  }
  if (lane < 4) {
    unsigned long long mv = m[0];
    mv = (lane == 1) ? m[1] : mv;
    mv = (lane == 2) ? m[2] : mv;
    mv = (lane == 3) ? m[3] : mv;
    int w = w0 + lane;
    xb2[((size_t)(w >> 1) * Bn + row) * 2 + (w & 1)] = mv;  // [XW/2][Bn][2]
  }
}

// One coalesced pass over W -> transposed row bitsets wbT[w][j] (u64, ballot over
// d-lanes) AND transposed column bitsets wt32[hw][d] (u32 over 32 j-rows each,
// per-thread bit accumulation, coalesced store). Padding comes out zero.
__global__ __launch_bounds__(256) void k_pack_w(const float* __restrict__ W,
                                                uint64_t* __restrict__ wbT,
                                                uint32_t* __restrict__ wt32) {
  int d = (int)blockIdx.x * 256 + (int)threadIdx.x;  // 0..5119
  int j0 = (int)blockIdx.y * 64;                     // 32 blocks of 64 j
  int lane = (int)(threadIdx.x & 63);
  int wv = (int)(threadIdx.x >> 6);                  // d-word sub-index in block
  uint64_t colbits = 0;
  for (int r = 0; r < 64; ++r) {
    int j = j0 + r;
    float v = (j < Hn && d < Dn) ? W[(size_t)j * Dn + d] : 0.0f;
    bool bit = v >= 0.5f;
    colbits |= ((uint64_t)(bit ? 1u : 0u)) << r;
    unsigned long long m = __ballot(bit);
    if (lane == 0) wbT[(size_t)(blockIdx.x * 4 + wv) * Hpad + j] = m;
  }
  wt32[(size_t)(blockIdx.y * 2) * Dpad + d] = (uint32_t)colbits;
  wt32[(size_t)(blockIdx.y * 2 + 1) * Dpad + d] = (uint32_t)(colbits >> 32);
}

// fwT[j][l] = sigmoid(2 * cw[l][j]), padded to 64 cols (pad = 0).
__global__ void k_pack_fwT(const float* __restrict__ cw, float* __restrict__ fwT) {
  int idx = blockIdx.x * blockDim.x + threadIdx.x;
  if (idx >= Hn * 64) return;
  int j = idx >> 6, l = idx & 63;
  float v = 0.0f;
  if (l < Ln) {
    float t = 2.0f * cw[(size_t)l * Hn + j];
    v = 1.0f / (1.0f + expf(-t));
  }
  fwT[idx] = v;
}

__global__ void k_zero(float* __restrict__ p, int n) {
  int i = blockIdx.x * blockDim.x + threadIdx.x;
  if (i < n) p[i] = 0.0f;
}

// Encoder: wave = 256 batch rows (4 per lane) x 8 hidden units.
// Per w2-iter: 4 coalesced dwordx4 x-loads + 8 broadcast ds_read_b128 (96 LDS cyc)
// + 256 VALU MAC insts (512 cyc) -> VALU-bound with ~80 VGPR state.
__global__ __launch_bounds__(256) void k_enc(const uint64_t* __restrict__ xb2,
                                             const uint64_t* __restrict__ wbT,
                                             const float* __restrict__ b_enc,
                                             const float* __restrict__ act0b,
                                             float* __restrict__ z_out,
                                             uint8_t* __restrict__ zb8) {
  __shared__ uint64_t wl[XW][8];  // 5120 B
  int tid = (int)threadIdx.x;
  int jg = (int)blockIdx.x;  // 0..255: j-group of 8
  int j0 = jg << 3;
#pragma unroll
  for (int k = 0; k < 3; ++k) {
    int idx = k * 256 + tid;
    if (idx < XW * 8) {
      int w = idx >> 3, j = idx & 7;
      wl[w][j] = wbT[(size_t)w * Hpad + j0 + j];
    }
  }
  __syncthreads();

  int wv = __builtin_amdgcn_readfirstlane(tid >> 6);
  int lane = tid & 63;
  int bg = (int)blockIdx.y * 4 + wv;  // 0..15: batch group of 256
  int b0 = (bg << 8) + lane;

  int acc[4][8] = {};
  const uint64_t* xp = xb2 + 2 * (size_t)b0;
#pragma unroll 1
  for (int w2 = 0; w2 < XW / 2; ++w2) {
    ulong2 xx[4];
#pragma unroll
    for (int i = 0; i < 4; ++i)
      xx[i] = *(const ulong2*)(xp + ((size_t)w2 * Bn + i * 64) * 2);
#pragma unroll
    for (int t2 = 0; t2 < 4; ++t2) {
      ulong2 wa = *(ulong2*)&wl[2 * w2][2 * t2];      // broadcast ds_read_b128
      ulong2 wb = *(ulong2*)&wl[2 * w2 + 1][2 * t2];  // broadcast ds_read_b128
#pragma unroll
      for (int i = 0; i < 4; ++i) {
        acc[i][2 * t2]     = popc_acc(xx[i].x & wa.x, acc[i][2 * t2]);
        acc[i][2 * t2 + 1] = popc_acc(xx[i].x & wa.y, acc[i][2 * t2 + 1]);
        acc[i][2 * t2]     = popc_acc(xx[i].y & wb.x, acc[i][2 * t2]);
        acc[i][2 * t2 + 1] = popc_acc(xx[i].y & wb.y, acc[i][2 * t2 + 1]);
      }
    }
  }

  float be[8], ab[8];
#pragma unroll
  for (int t = 0; t < 8; ++t) {
    int j = j0 + t;
    int js = (j < Hn) ? j : (Hn - 1);
    be[t] = b_enc[js];
    ab[t] = act0b[js];
  }
#pragma unroll
  for (int i = 0; i < 4; ++i) {
    int b = b0 + i * 64;
    uint32_t zbyte = 0;
    float zf[8];
#pragma unroll
    for (int t = 0; t < 8; ++t) {
      int j = j0 + t;
      // exact: integer-valued acc + b_enc, then + act0_bias (reference order)
      float h = ((float)acc[i][t] + be[t]) + ab[t];
      bool zb = (j < Hn) && (h >= 1.0f);
      zbyte |= zb ? (1u << t) : 0u;
      zf[t] = zb ? 1.0f : 0.0f;
    }
    // byte (jg&3) of u32 word hw = jg>>2 in [hw][Bn] layout (little-endian match)
    zb8[((size_t)(jg >> 2) * Bn + b) * 4 + (jg & 3)] = (uint8_t)zbyte;
    if (j0 < Hn) {  // 2000 % 8 == 0: group fully valid or fully padded
      float* zp = z_out + (size_t)b * Hn + j0;
      *(float4*)zp = make_float4(zf[0], zf[1], zf[2], zf[3]);
      *(float4*)(zp + 4) = make_float4(zf[4], zf[5], zf[6], zf[7]);
    }
  }
}

// Decoder: mirror of encoder. Wave = 256 batch rows (4 per lane) x 8 outputs.
// Per hw-iter: 4 coalesced z-word loads + 2 broadcast ds_read_b128 (24 LDS cyc)
// + 128 VALU MAC insts (256 cyc). acc[4][8]=32 regs -> high occupancy.
__global__ __launch_bounds__(256) void k_dec(const uint32_t* __restrict__ zb32,
                                             const uint32_t* __restrict__ wt32,
                                             const float* __restrict__ act3b,
                                             float* __restrict__ out) {
  __shared__ uint32_t tl[64][8];  // 2048 B
  int tid = (int)threadIdx.x;
  int dc = (int)blockIdx.x;  // 0..639: d-chunk of 8
  int d0 = dc << 3;
  {
    int idx = tid;  // 0..255 covers 512 entries in 2 steps
#pragma unroll
    for (int k = 0; k < 2; ++k) {
      int e = k * 256 + idx;
      int hw = e >> 3, dl = e & 7;
      tl[hw][dl] = wt32[(size_t)hw * Dpad + d0 + dl];
    }
  }
  __syncthreads();

  int wv = __builtin_amdgcn_readfirstlane(tid >> 6);
  int lane = tid & 63;
  int bg = (int)blockIdx.y * 4 + wv;  // 0..15: batch group of 256
  int b0 = (bg << 8) + lane;

  int acc[4][8] = {};
  const uint32_t* zp = zb32 + b0;
#pragma unroll 2
  for (int hw = 0; hw < 64; ++hw) {
    uint32_t zw[4];
#pragma unroll
    for (int i = 0; i < 4; ++i) zw[i] = zp[(size_t)hw * Bn + i * 64];
    uint4 wA = *(uint4*)&tl[hw][0];  // broadcast ds_read_b128
    uint4 wB = *(uint4*)&tl[hw][4];  // broadcast ds_read_b128
#pragma unroll
    for (int i = 0; i < 4; ++i) {
      acc[i][0] = __builtin_popcount(zw[i] & wA.x) + acc[i][0];
      acc[i][1] = __builtin_popcount(zw[i] & wA.y) + acc[i][1];
      acc[i][2] = __builtin_popcount(zw[i] & wA.z) + acc[i][2];
      acc[i][3] = __builtin_popcount(zw[i] & wA.w) + acc[i][3];
      acc[i][4] = __builtin_popcount(zw[i] & wB.x) + acc[i][4];
      acc[i][5] = __builtin_popcount(zw[i] & wB.y) + acc[i][5];
      acc[i][6] = __builtin_popcount(zw[i] & wB.z) + acc[i][6];
      acc[i][7] = __builtin_popcount(zw[i] & wB.w) + acc[i][7];
    }
  }

  float ab[8];
#pragma unroll
  for (int t = 0; t < 8; ++t) {
    int d = d0 + t;
    int ds = (d < Dn) ? d : (Dn - 1);
    ab[t] = act3b[ds];
  }
  if (d0 < Dn) {  // 5000 % 8 == 0: chunk fully valid or fully padded
#pragma unroll
    for (int i = 0; i < 4; ++i) {
      int b = b0 + i * 64;
      float of[8];
#pragma unroll
      for (int t = 0; t < 8; ++t)
        of[t] = (((float)acc[i][t] + ab[t]) >= 1.0f) ? 1.0f : 0.0f;
      float* op = out + (size_t)b * Dn + d0;
      *(float4*)op = make_float4(of[0], of[1], of[2], of[3]);
      *(float4*)(op + 4) = make_float4(of[4], of[5], of[6], of[7]);
    }
  }
}

// classification = z @ fwT: LDS-tiled outer-product GEMM.
// Block = 128 b-rows x 64 l x 256 j-slice (4 tiles of 64 j). Thread = 8b x 4l.
__global__ __launch_bounds__(256) void k_cls(const float* __restrict__ z,
                                             const float* __restrict__ fwT,
                                             float* __restrict__ cls) {
  __shared__ float zT[64][132];   // transposed z tile, padded stride
  __shared__ float fwL[64][64];   // fw tile
  int tid = (int)threadIdx.x;
  int bb0 = (int)blockIdx.x * 128;
  int jsp = (int)blockIdx.y;      // 0..7
  int tx = tid & 15, ty = tid >> 4;
  float acc[8][4] = {};

  for (int tile = 0; tile < 4; ++tile) {
    int jt0 = jsp * 256 + tile * 64;
    __syncthreads();
#pragma unroll
    for (int k = 0; k < 8; ++k) {
      int idx = k * 256 + tid;
      int r = idx >> 4, c4 = idx & 15;
      int j = jt0 + c4 * 4;
      float4 v = make_float4(0.f, 0.f, 0.f, 0.f);
      if (j < Hn) v = *(const float4*)(z + (size_t)(bb0 + r) * Hn + j);
      zT[c4 * 4 + 0][r] = v.x;
      zT[c4 * 4 + 1][r] = v.y;
      zT[c4 * 4 + 2][r] = v.z;
      zT[c4 * 4 + 3][r] = v.w;
    }
#pragma unroll
    for (int k = 0; k < 4; ++k) {
      int idx = k * 256 + tid;
      int jj = idx >> 4, c4 = idx & 15;
      int j = jt0 + jj;
      float4 v = make_float4(0.f, 0.f, 0.f, 0.f);
      if (j < Hn) v = *(const float4*)(fwT + (size_t)j * 64 + c4 * 4);
      *(float4*)&fwL[jj][c4 * 4] = v;
    }
    __syncthreads();
#pragma unroll 4
    for (int jj = 0; jj < 64; ++jj) {
      float4 fv = *(float4*)&fwL[jj][tx * 4];
      float4 za = *(float4*)&zT[jj][ty * 8];
      float4 zb = *(float4*)&zT[jj][ty * 8 + 4];
      float zz[8] = {za.x, za.y, za.z, za.w, zb.x, zb.y, zb.z, zb.w};
      float ff[4] = {fv.x, fv.y, fv.z, fv.w};
#pragma unroll
      for (int i = 0; i < 8; ++i)
#pragma unroll
        for (int l = 0; l < 4; ++l) acc[i][l] += zz[i] * ff[l];
    }
  }

#pragma unroll
  for (int i = 0; i < 8; ++i) {
    int b = bb0 + ty * 8 + i;
#pragma unroll
    for (int l = 0; l < 4; ++l) {
      int L = tx * 4 + l;
      if (L < Ln) atomicAdd(&cls[(size_t)b * Ln + L], acc[i][l]);
    }
  }
}

extern "C" void kernel_launch(void* const* d_in, const int* in_sizes, int n_in,
                              void* d_out, int out_size, void* d_ws, size_t ws_size,
                              hipStream_t stream) {
  const float* x     = (const float*)d_in[0];  // [B][D]
  const float* W     = (const float*)d_in[1];  // [H][D]
  const float* b_enc = (const float*)d_in[2];  // [H]
  const float* act0b = (const float*)d_in[3];  // [H]
  const float* act3b = (const float*)d_in[4];  // [D]
  const float* cw    = (const float*)d_in[5];  // [L][H]

  float* out0 = (float*)d_out;              // output        [B][D]
  float* cls  = out0 + (size_t)Bn * Dn;     // classification[B][L]
  float* zout = cls + (size_t)Bn * Ln;      // z             [B][H]

  // Workspace (~6.8 MB).
  char* ws = (char*)d_ws;
  uint64_t* xb2  = (uint64_t*)ws; ws += (size_t)XW * Bn * 8;    // 2.62 MB [40][Bn][2]
  uint64_t* wbT  = (uint64_t*)ws; ws += (size_t)XW * Hpad * 8;  // 1.31 MB [80][Hpad]
  uint32_t* wt32 = (uint32_t*)ws; ws += (size_t)64 * Dpad * 4;  // 1.31 MB [64][Dpad]
  uint32_t* zb32 = (uint32_t*)ws; ws += (size_t)64 * Bn * 4;    // 1.05 MB [64][Bn] u32 (byte-assembled)
  float*    fwT  = (float*)ws;    ws += (size_t)Hn * 64 * 4;    // 0.51 MB

  {  // x -> xb2 (paired word-major transpose)
    long long waves = (long long)Bn * (XW / 4);
    k_pack_x<<<(int)((waves * 64 + 255) / 256), 256, 0, stream>>>(x, xb2);
  }
  {  // W -> wbT + wt32 in one coalesced pass
    dim3 gw2(Dpad / 256, Hpad / 64);  // (20, 32)
    k_pack_w<<<gw2, 256, 0, stream>>>(W, wbT, wt32);
  }
  k_pack_fwT<<<(Hn * 64 + 255) / 256, 256, 0, stream>>>(cw, fwT);
  k_zero<<<(Bn * Ln + 255) / 256, 256, 0, stream>>>(cls, Bn * Ln);

  // enc: 256 j-groups x 16 batch groups (4 waves/block) = 4096 waves
  dim3 g1(256, 4);
  k_enc<<<g1, 256, 0, stream>>>(xb2, wbT, b_enc, act0b, zout, (uint8_t*)zb32);

  // cls: 32 b-blocks x 8 j-splits = 256 blocks
  dim3 g3(32, 8);
  k_cls<<<g3, 256, 0, stream>>>(zout, fwT, cls);

  // dec: 640 d-chunks x 16 batch groups (4 waves/block) = 10240 waves
  dim3 g2(640, 4);
  k_dec<<<g2, 256, 0, stream>>>(zb32, wt32, act3b, out0);
}

// Round 10
// 302.440 us; speedup vs baseline: 1.2407x; 1.0793x over previous
//
#include <hip/hip_runtime.h>
#include <stdint.h>

// Problem sizes.
static constexpr int Bn = 4096;
static constexpr int Dn = 5000;
static constexpr int Hn = 2000;
static constexpr int Ln = 50;
static constexpr int XW = 80;      // u64 words covering D (5120 bits >= 5000)
static constexpr int Hpad = 2048;  // padded H bit capacity (64 u32 words)
static constexpr int Dpad = 5120;  // padded D = XW*64

__device__ __forceinline__ int popc_acc(uint64_t v, int acc) {
  // 2x v_and_b32 + 2x v_bcnt_u32_b32 (fused accumulate)
  acc = __builtin_popcount((uint32_t)v) + acc;
  acc = __builtin_popcount((uint32_t)(v >> 32)) + acc;
  return acc;
}

// Pack x rows into word-PAIRED transposed bit matrix xb2[w2][b][2] (ulong2) so the
// encoder loads 16B per 2 K-words. 4 words/wave, coalesced reads.
__global__ void k_pack_x(const float* __restrict__ x, uint64_t* __restrict__ xb2) {
  int g = (int)((blockIdx.x * blockDim.x + threadIdx.x) >> 6);
  int lane = (int)(threadIdx.x & 63);
  constexpr int nq = XW >> 2;  // 20
  int row = g / nq;
  int q = g - row * nq;
  if (row >= Bn) return;
  int w0 = q << 2;
  unsigned long long m[4];
#pragma unroll
  for (int e = 0; e < 4; ++e) {
    int col = ((w0 + e) << 6) + lane;
    float v = (col < Dn) ? x[(size_t)row * Dn + col] : 0.0f;
    m[e] = __ballot(v >= 0.5f);
  }
  if (lane < 4) {
    unsigned long long mv = m[0];
    mv = (lane == 1) ? m[1] : mv;
    mv = (lane == 2) ? m[2] : mv;
    mv = (lane == 3) ? m[3] : mv;
    int w = w0 + lane;
    xb2[((size_t)(w >> 1) * Bn + row) * 2 + (w & 1)] = mv;  // [XW/2][Bn][2]
  }
}

// One coalesced pass over W -> transposed row bitsets wbT[w][j] (u64, ballot over
// d-lanes) AND transposed column bitsets wt32[hw][d] (u32 over 32 j-rows each,
// per-thread bit accumulation, coalesced store). Padding comes out zero.
__global__ __launch_bounds__(256) void k_pack_w(const float* __restrict__ W,
                                                uint64_t* __restrict__ wbT,
                                                uint32_t* __restrict__ wt32) {
  int d = (int)blockIdx.x * 256 + (int)threadIdx.x;  // 0..5119
  int j0 = (int)blockIdx.y * 64;                     // 32 blocks of 64 j
  int lane = (int)(threadIdx.x & 63);
  int wv = (int)(threadIdx.x >> 6);                  // d-word sub-index in block
  uint64_t colbits = 0;
  for (int r = 0; r < 64; ++r) {
    int j = j0 + r;
    float v = (j < Hn && d < Dn) ? W[(size_t)j * Dn + d] : 0.0f;
    bool bit = v >= 0.5f;
    colbits |= ((uint64_t)(bit ? 1u : 0u)) << r;
    unsigned long long m = __ballot(bit);
    if (lane == 0) wbT[(size_t)(blockIdx.x * 4 + wv) * Hpad + j] = m;
  }
  wt32[(size_t)(blockIdx.y * 2) * Dpad + d] = (uint32_t)colbits;
  wt32[(size_t)(blockIdx.y * 2 + 1) * Dpad + d] = (uint32_t)(colbits >> 32);
}

// fwT[j][l] = sigmoid(2 * cw[l][j]), padded to 64 cols (pad = 0).
__global__ void k_pack_fwT(const float* __restrict__ cw, float* __restrict__ fwT) {
  int idx = blockIdx.x * blockDim.x + threadIdx.x;
  if (idx >= Hn * 64) return;
  int j = idx >> 6, l = idx & 63;
  float v = 0.0f;
  if (l < Ln) {
    float t = 2.0f * cw[(size_t)l * Hn + j];
    v = 1.0f / (1.0f + expf(-t));
  }
  fwT[idx] = v;
}

__global__ void k_zero(float* __restrict__ p, int n) {
  int i = blockIdx.x * blockDim.x + threadIdx.x;
  if (i < n) p[i] = 0.0f;
}

// Encoder: wave = 256 batch rows (4 per lane) x 8 hidden units, with an explicit
// 2-deep software pipeline: next-step weights (ds_read_b128) and next-iter x words
// (global dwordx4) are issued BEFORE the current MAC block, so waitcnts land
// behind 128-256 VALU cycles instead of inside every step.
__global__ __launch_bounds__(256, 3) void k_enc(const uint64_t* __restrict__ xb2,
                                                const uint64_t* __restrict__ wbT,
                                                const float* __restrict__ b_enc,
                                                const float* __restrict__ act0b,
                                                float* __restrict__ z_out,
                                                uint8_t* __restrict__ zb8) {
  __shared__ uint64_t wl[XW][8];  // 5120 B
  int tid = (int)threadIdx.x;
  int jg = (int)blockIdx.x;  // 0..255: j-group of 8
  int j0 = jg << 3;
#pragma unroll
  for (int k = 0; k < 3; ++k) {
    int idx = k * 256 + tid;
    if (idx < XW * 8) {
      int w = idx >> 3, j = idx & 7;
      wl[w][j] = wbT[(size_t)w * Hpad + j0 + j];
    }
  }
  __syncthreads();

  int wv = __builtin_amdgcn_readfirstlane(tid >> 6);
  int lane = tid & 63;
  int bg = (int)blockIdx.y * 4 + wv;  // 0..15: batch group of 256
  int b0 = (bg << 8) + lane;

  int acc[4][8] = {};
  const uint64_t* xp = xb2 + 2 * (size_t)b0;

  // pipeline state
  ulong2 xx0, xx1, xx2, xx3;      // current x words (2 K-words x 4 batch rows)
  ulong2 xn0, xn1, xn2, xn3;      // next-iter x words
  ulong2 wac, wbc, wan, wbn;      // current / next weight pairs

  xx0 = *(const ulong2*)(xp + 0 * 128);
  xx1 = *(const ulong2*)(xp + 1 * 128);
  xx2 = *(const ulong2*)(xp + 2 * 128);
  xx3 = *(const ulong2*)(xp + 3 * 128);
  wac = *(const ulong2*)&wl[0][0];
  wbc = *(const ulong2*)&wl[1][0];

#define ENC_MAC(T2)                                            \
  do {                                                         \
    acc[0][2*(T2)]   = popc_acc(xx0.x & wac.x, acc[0][2*(T2)]);   \
    acc[0][2*(T2)+1] = popc_acc(xx0.x & wac.y, acc[0][2*(T2)+1]); \
    acc[0][2*(T2)]   = popc_acc(xx0.y & wbc.x, acc[0][2*(T2)]);   \
    acc[0][2*(T2)+1] = popc_acc(xx0.y & wbc.y, acc[0][2*(T2)+1]); \
    acc[1][2*(T2)]   = popc_acc(xx1.x & wac.x, acc[1][2*(T2)]);   \
    acc[1][2*(T2)+1] = popc_acc(xx1.x & wac.y, acc[1][2*(T2)+1]); \
    acc[1][2*(T2)]   = popc_acc(xx1.y & wbc.x, acc[1][2*(T2)]);   \
    acc[1][2*(T2)+1] = popc_acc(xx1.y & wbc.y, acc[1][2*(T2)+1]); \
    acc[2][2*(T2)]   = popc_acc(xx2.x & wac.x, acc[2][2*(T2)]);   \
    acc[2][2*(T2)+1] = popc_acc(xx2.x & wac.y, acc[2][2*(T2)+1]); \
    acc[2][2*(T2)]   = popc_acc(xx2.y & wbc.x, acc[2][2*(T2)]);   \
    acc[2][2*(T2)+1] = popc_acc(xx2.y & wbc.y, acc[2][2*(T2)+1]); \
    acc[3][2*(T2)]   = popc_acc(xx3.x & wac.x, acc[3][2*(T2)]);   \
    acc[3][2*(T2)+1] = popc_acc(xx3.x & wac.y, acc[3][2*(T2)+1]); \
    acc[3][2*(T2)]   = popc_acc(xx3.y & wbc.x, acc[3][2*(T2)]);   \
    acc[3][2*(T2)+1] = popc_acc(xx3.y & wbc.y, acc[3][2*(T2)+1]); \
  } while (0)

#pragma unroll 1
  for (int w2 = 0; w2 < XW / 2; ++w2) {
    int w2n = (w2 < XW / 2 - 1) ? w2 + 1 : w2;  // clamped: last iter re-reads
    const uint64_t* xq = xp + (size_t)w2n * (2 * Bn);
    // issue next-iter x loads (VMEM) early
    xn0 = *(const ulong2*)(xq + 0 * 128);
    xn1 = *(const ulong2*)(xq + 1 * 128);
    xn2 = *(const ulong2*)(xq + 2 * 128);
    xn3 = *(const ulong2*)(xq + 3 * 128);
    // t2 = 0..3, prefetching the next weight pair each step
    wan = *(const ulong2*)&wl[2 * w2][2];
    wbn = *(const ulong2*)&wl[2 * w2 + 1][2];
    ENC_MAC(0); wac = wan; wbc = wbn;
    wan = *(const ulong2*)&wl[2 * w2][4];
    wbn = *(const ulong2*)&wl[2 * w2 + 1][4];
    ENC_MAC(1); wac = wan; wbc = wbn;
    wan = *(const ulong2*)&wl[2 * w2][6];
    wbn = *(const ulong2*)&wl[2 * w2 + 1][6];
    ENC_MAC(2); wac = wan; wbc = wbn;
    wan = *(const ulong2*)&wl[2 * w2n][0];
    wbn = *(const ulong2*)&wl[2 * w2n + 1][0];
    ENC_MAC(3); wac = wan; wbc = wbn;
    xx0 = xn0; xx1 = xn1; xx2 = xn2; xx3 = xn3;
  }
#undef ENC_MAC

  float be[8], ab[8];
#pragma unroll
  for (int t = 0; t < 8; ++t) {
    int j = j0 + t;
    int js = (j < Hn) ? j : (Hn - 1);
    be[t] = b_enc[js];
    ab[t] = act0b[js];
  }
#pragma unroll
  for (int i = 0; i < 4; ++i) {
    int b = b0 + i * 64;
    uint32_t zbyte = 0;
    float zf[8];
#pragma unroll
    for (int t = 0; t < 8; ++t) {
      int j = j0 + t;
      // exact: integer-valued acc + b_enc, then + act0_bias (reference order)
      float h = ((float)acc[i][t] + be[t]) + ab[t];
      bool zb = (j < Hn) && (h >= 1.0f);
      zbyte |= zb ? (1u << t) : 0u;
      zf[t] = zb ? 1.0f : 0.0f;
    }
    // byte (jg&3) of u32 word hw = jg>>2 in [hw][Bn] layout (little-endian match)
    zb8[((size_t)(jg >> 2) * Bn + b) * 4 + (jg & 3)] = (uint8_t)zbyte;
    if (j0 < Hn) {  // 2000 % 8 == 0: group fully valid or fully padded
      float* zp = z_out + (size_t)b * Hn + j0;
      *(float4*)zp = make_float4(zf[0], zf[1], zf[2], zf[3]);
      *(float4*)(zp + 4) = make_float4(zf[4], zf[5], zf[6], zf[7]);
    }
  }
}

// Decoder: wave = 256 batch rows (4 per lane) x 8 outputs, 2-deep pipelined:
// next hw-step's z words + weight columns issued before current MACs.
__global__ __launch_bounds__(256, 6) void k_dec(const uint32_t* __restrict__ zb32,
                                                const uint32_t* __restrict__ wt32,
                                                const float* __restrict__ act3b,
                                                float* __restrict__ out) {
  __shared__ uint32_t tl[64][8];  // 2048 B
  int tid = (int)threadIdx.x;
  int dc = (int)blockIdx.x;  // 0..639: d-chunk of 8
  int d0 = dc << 3;
  {
#pragma unroll
    for (int k = 0; k < 2; ++k) {
      int e = k * 256 + tid;
      int hw = e >> 3, dl = e & 7;
      tl[hw][dl] = wt32[(size_t)hw * Dpad + d0 + dl];
    }
  }
  __syncthreads();

  int wv = __builtin_amdgcn_readfirstlane(tid >> 6);
  int lane = tid & 63;
  int bg = (int)blockIdx.y * 4 + wv;  // 0..15: batch group of 256
  int b0 = (bg << 8) + lane;

  int acc[4][8] = {};
  const uint32_t* zp = zb32 + b0;

  uint32_t z0, z1, z2, z3, n0, n1, n2, n3;
  uint4 wA, wB, wAn, wBn;
  z0 = zp[0];
  z1 = zp[64];
  z2 = zp[128];
  z3 = zp[192];
  wA = *(const uint4*)&tl[0][0];
  wB = *(const uint4*)&tl[0][4];

#define DEC_MAC()                                       \
  do {                                                  \
    acc[0][0] = __builtin_popcount(z0 & wA.x) + acc[0][0]; \
    acc[0][1] = __builtin_popcount(z0 & wA.y) + acc[0][1]; \
    acc[0][2] = __builtin_popcount(z0 & wA.z) + acc[0][2]; \
    acc[0][3] = __builtin_popcount(z0 & wA.w) + acc[0][3]; \
    acc[0][4] = __builtin_popcount(z0 & wB.x) + acc[0][4]; \
    acc[0][5] = __builtin_popcount(z0 & wB.y) + acc[0][5]; \
    acc[0][6] = __builtin_popcount(z0 & wB.z) + acc[0][6]; \
    acc[0][7] = __builtin_popcount(z0 & wB.w) + acc[0][7]; \
    acc[1][0] = __builtin_popcount(z1 & wA.x) + acc[1][0]; \
    acc[1][1] = __builtin_popcount(z1 & wA.y) + acc[1][1]; \
    acc[1][2] = __builtin_popcount(z1 & wA.z) + acc[1][2]; \
    acc[1][3] = __builtin_popcount(z1 & wA.w) + acc[1][3]; \
    acc[1][4] = __builtin_popcount(z1 & wB.x) + acc[1][4]; \
    acc[1][5] = __builtin_popcount(z1 & wB.y) + acc[1][5]; \
    acc[1][6] = __builtin_popcount(z1 & wB.z) + acc[1][6]; \
    acc[1][7] = __builtin_popcount(z1 & wB.w) + acc[1][7]; \
    acc[2][0] = __builtin_popcount(z2 & wA.x) + acc[2][0]; \
    acc[2][1] = __builtin_popcount(z2 & wA.y) + acc[2][1]; \
    acc[2][2] = __builtin_popcount(z2 & wA.z) + acc[2][2]; \
    acc[2][3] = __builtin_popcount(z2 & wA.w) + acc[2][3]; \
    acc[2][4] = __builtin_popcount(z2 & wB.x) + acc[2][4]; \
    acc[2][5] = __builtin_popcount(z2 & wB.y) + acc[2][5]; \
    acc[2][6] = __builtin_popcount(z2 & wB.z) + acc[2][6]; \
    acc[2][7] = __builtin_popcount(z2 & wB.w) + acc[2][7]; \
    acc[3][0] = __builtin_popcount(z3 & wA.x) + acc[3][0]; \
    acc[3][1] = __builtin_popcount(z3 & wA.y) + acc[3][1]; \
    acc[3][2] = __builtin_popcount(z3 & wA.z) + acc[3][2]; \
    acc[3][3] = __builtin_popcount(z3 & wA.w) + acc[3][3]; \
    acc[3][4] = __builtin_popcount(z3 & wB.x) + acc[3][4]; \
    acc[3][5] = __builtin_popcount(z3 & wB.y) + acc[3][5]; \
    acc[3][6] = __builtin_popcount(z3 & wB.z) + acc[3][6]; \
    acc[3][7] = __builtin_popcount(z3 & wB.w) + acc[3][7]; \
  } while (0)

#pragma unroll 1
  for (int hw = 0; hw < 64; ++hw) {
    int hn = (hw < 63) ? hw + 1 : hw;  // clamped: last iter re-reads
    const uint32_t* zq = zp + (size_t)hn * Bn;
    n0 = zq[0];
    n1 = zq[64];
    n2 = zq[128];
    n3 = zq[192];
    wAn = *(const uint4*)&tl[hn][0];
    wBn = *(const uint4*)&tl[hn][4];
    DEC_MAC();
    z0 = n0; z1 = n1; z2 = n2; z3 = n3;
    wA = wAn; wB = wBn;
  }
#undef DEC_MAC

  float ab[8];
#pragma unroll
  for (int t = 0; t < 8; ++t) {
    int d = d0 + t;
    int ds = (d < Dn) ? d : (Dn - 1);
    ab[t] = act3b[ds];
  }
  if (d0 < Dn) {  // 5000 % 8 == 0: chunk fully valid or fully padded
#pragma unroll
    for (int i = 0; i < 4; ++i) {
      int b = b0 + i * 64;
      float of[8];
#pragma unroll
      for (int t = 0; t < 8; ++t)
        of[t] = (((float)acc[i][t] + ab[t]) >= 1.0f) ? 1.0f : 0.0f;
      float* op = out + (size_t)b * Dn + d0;
      *(float4*)op = make_float4(of[0], of[1], of[2], of[3]);
      *(float4*)(op + 4) = make_float4(of[4], of[5], of[6], of[7]);
    }
  }
}

// classification = z @ fwT: LDS-tiled outer-product GEMM.
// Block = 128 b-rows x 64 l x 256 j-slice (4 tiles of 64 j). Thread = 8b x 4l.
__global__ __launch_bounds__(256) void k_cls(const float* __restrict__ z,
                                             const float* __restrict__ fwT,
                                             float* __restrict__ cls) {
  __shared__ float zT[64][132];   // transposed z tile, padded stride
  __shared__ float fwL[64][64];   // fw tile
  int tid = (int)threadIdx.x;
  int bb0 = (int)blockIdx.x * 128;
  int jsp = (int)blockIdx.y;      // 0..7
  int tx = tid & 15, ty = tid >> 4;
  float acc[8][4] = {};

  for (int tile = 0; tile < 4; ++tile) {
    int jt0 = jsp * 256 + tile * 64;
    __syncthreads();
#pragma unroll
    for (int k = 0; k < 8; ++k) {
      int idx = k * 256 + tid;
      int r = idx >> 4, c4 = idx & 15;
      int j = jt0 + c4 * 4;
      float4 v = make_float4(0.f, 0.f, 0.f, 0.f);
      if (j < Hn) v = *(const float4*)(z + (size_t)(bb0 + r) * Hn + j);
      zT[c4 * 4 + 0][r] = v.x;
      zT[c4 * 4 + 1][r] = v.y;
      zT[c4 * 4 + 2][r] = v.z;
      zT[c4 * 4 + 3][r] = v.w;
    }
#pragma unroll
    for (int k = 0; k < 4; ++k) {
      int idx = k * 256 + tid;
      int jj = idx >> 4, c4 = idx & 15;
      int j = jt0 + jj;
      float4 v = make_float4(0.f, 0.f, 0.f, 0.f);
      if (j < Hn) v = *(const float4*)(fwT + (size_t)j * 64 + c4 * 4);
      *(float4*)&fwL[jj][c4 * 4] = v;
    }
    __syncthreads();
#pragma unroll 4
    for (int jj = 0; jj < 64; ++jj) {
      float4 fv = *(float4*)&fwL[jj][tx * 4];
      float4 za = *(float4*)&zT[jj][ty * 8];
      float4 zb = *(float4*)&zT[jj][ty * 8 + 4];
      float zz[8] = {za.x, za.y, za.z, za.w, zb.x, zb.y, zb.z, zb.w};
      float ff[4] = {fv.x, fv.y, fv.z, fv.w};
#pragma unroll
      for (int i = 0; i < 8; ++i)
#pragma unroll
        for (int l = 0; l < 4; ++l) acc[i][l] += zz[i] * ff[l];
    }
  }

#pragma unroll
  for (int i = 0; i < 8; ++i) {
    int b = bb0 + ty * 8 + i;
#pragma unroll
    for (int l = 0; l < 4; ++l) {
      int L = tx * 4 + l;
      if (L < Ln) atomicAdd(&cls[(size_t)b * Ln + L], acc[i][l]);
    }
  }
}

extern "C" void kernel_launch(void* const* d_in, const int* in_sizes, int n_in,
                              void* d_out, int out_size, void* d_ws, size_t ws_size,
                              hipStream_t stream) {
  const float* x     = (const float*)d_in[0];  // [B][D]
  const float* W     = (const float*)d_in[1];  // [H][D]
  const float* b_enc = (const float*)d_in[2];  // [H]
  const float* act0b = (const float*)d_in[3];  // [H]
  const float* act3b = (const float*)d_in[4];  // [D]
  const float* cw    = (const float*)d_in[5];  // [L][H]

  float* out0 = (float*)d_out;              // output        [B][D]
  float* cls  = out0 + (size_t)Bn * Dn;     // classification[B][L]
  float* zout = cls + (size_t)Bn * Ln;      // z             [B][H]

  // Workspace (~6.8 MB).
  char* ws = (char*)d_ws;
  uint64_t* xb2  = (uint64_t*)ws; ws += (size_t)XW * Bn * 8;    // 2.62 MB [40][Bn][2]
  uint64_t* wbT  = (uint64_t*)ws; ws += (size_t)XW * Hpad * 8;  // 1.31 MB [80][Hpad]
  uint32_t* wt32 = (uint32_t*)ws; ws += (size_t)64 * Dpad * 4;  // 1.31 MB [64][Dpad]
  uint32_t* zb32 = (uint32_t*)ws; ws += (size_t)64 * Bn * 4;    // 1.05 MB [64][Bn] u32 (byte-assembled)
  float*    fwT  = (float*)ws;    ws += (size_t)Hn * 64 * 4;    // 0.51 MB

  {  // x -> xb2 (paired word-major transpose)
    long long waves = (long long)Bn * (XW / 4);
    k_pack_x<<<(int)((waves * 64 + 255) / 256), 256, 0, stream>>>(x, xb2);
  }
  {  // W -> wbT + wt32 in one coalesced pass
    dim3 gw2(Dpad / 256, Hpad / 64);  // (20, 32)
    k_pack_w<<<gw2, 256, 0, stream>>>(W, wbT, wt32);
  }
  k_pack_fwT<<<(Hn * 64 + 255) / 256, 256, 0, stream>>>(cw, fwT);
  k_zero<<<(Bn * Ln + 255) / 256, 256, 0, stream>>>(cls, Bn * Ln);

  // enc: 256 j-groups x 16 batch groups (4 waves/block) = 4096 waves
  dim3 g1(256, 4);
  k_enc<<<g1, 256, 0, stream>>>(xb2, wbT, b_enc, act0b, zout, (uint8_t*)zb32);

  // cls: 32 b-blocks x 8 j-splits = 256 blocks
  dim3 g3(32, 8);
  k_cls<<<g3, 256, 0, stream>>>(zout, fwT, cls);

  // dec: 640 d-chunks x 16 batch groups (4 waves/block) = 10240 waves
  dim3 g2(640, 4);
  k_dec<<<g2, 256, 0, stream>>>(zb32, wt32, act3b, out0);
}

// Round 11
// 289.918 us; speedup vs baseline: 1.2943x; 1.0432x over previous
//
#include <hip/hip_runtime.h>
#include <stdint.h>

// Problem sizes.
static constexpr int Bn = 4096;
static constexpr int Dn = 5000;
static constexpr int Hn = 2000;
static constexpr int Ln = 50;
static constexpr int XW = 80;      // u64 words covering D (5120 bits >= 5000)
static constexpr int Hpad = 2048;  // padded H bit capacity (64 u32 words)
static constexpr int Dpad = 5120;  // padded D = XW*64

__device__ __forceinline__ int popc_acc(uint64_t v, int acc) {
  // 2x v_and_b32 + 2x v_bcnt_u32_b32 (fused accumulate)
  acc = __builtin_popcount((uint32_t)v) + acc;
  acc = __builtin_popcount((uint32_t)(v >> 32)) + acc;
  return acc;
}

// Pack x rows into word-PAIRED transposed bit matrix xb2[w2][b][2] (ulong2) so the
// encoder loads 16B per 2 K-words. 4 words/wave, coalesced reads.
__global__ void k_pack_x(const float* __restrict__ x, uint64_t* __restrict__ xb2) {
  int g = (int)((blockIdx.x * blockDim.x + threadIdx.x) >> 6);
  int lane = (int)(threadIdx.x & 63);
  constexpr int nq = XW >> 2;  // 20
  int row = g / nq;
  int q = g - row * nq;
  if (row >= Bn) return;
  int w0 = q << 2;
  unsigned long long m[4];
#pragma unroll
  for (int e = 0; e < 4; ++e) {
    int col = ((w0 + e) << 6) + lane;
    float v = (col < Dn) ? x[(size_t)row * Dn + col] : 0.0f;
    m[e] = __ballot(v >= 0.5f);
  }
  if (lane < 4) {
    unsigned long long mv = m[0];
    mv = (lane == 1) ? m[1] : mv;
    mv = (lane == 2) ? m[2] : mv;
    mv = (lane == 3) ? m[3] : mv;
    int w = w0 + lane;
    xb2[((size_t)(w >> 1) * Bn + row) * 2 + (w & 1)] = mv;  // [XW/2][Bn][2]
  }
}

// Ballot-only pack of W rows -> wbT[w][j] (transposed store). Memory-bound:
// one coalesced float read + 1 cmp + 1 ballot per 64 bits. No per-thread colbits.
__global__ void k_pack_w(const float* __restrict__ W, uint64_t* __restrict__ wbT) {
  int g = (int)((blockIdx.x * blockDim.x + threadIdx.x) >> 6);
  int lane = (int)(threadIdx.x & 63);
  constexpr int nq = XW >> 2;  // 20
  int row = g / nq;            // j
  int q = g - row * nq;
  if (row >= Hn) return;
  int w0 = q << 2;
  unsigned long long m[4];
#pragma unroll
  for (int e = 0; e < 4; ++e) {
    int col = ((w0 + e) << 6) + lane;
    float v = (col < Dn) ? W[(size_t)row * Dn + col] : 0.0f;
    m[e] = __ballot(v >= 0.5f);
  }
  if (lane < 4) {
    unsigned long long mv = m[0];
    mv = (lane == 1) ? m[1] : mv;
    mv = (lane == 2) ? m[2] : mv;
    mv = (lane == 3) ? m[3] : mv;
    wbT[(size_t)(w0 + lane) * Hpad + row] = mv;
  }
}

// Cross-lane 64x64 bit transpose: wbT[w][j] -> wt32[hw][d].
// Wave = (jc: 64-j chunk, w: d-word). Lane l loads wbT[w][jc*64+l]; for e in 0..63
// ballot bit-plane e; lane e keeps the mask. Lane l ends with the column bits for
// d = w*64+l over j = jc*64..+63, stored as two coalesced u32 rows.
// Padded j rows (>=2000) contribute garbage bits; they are masked by z bits == 0.
__global__ void k_transp(const uint64_t* __restrict__ wbT, uint32_t* __restrict__ wt32) {
  int g = (int)((blockIdx.x * blockDim.x + threadIdx.x) >> 6);
  int lane = (int)(threadIdx.x & 63);
  int jc = g >> 0;  // decompose below
  int w = jc % XW;
  jc = jc / XW;     // 0..31
  if (jc >= Hpad / 64) return;
  uint64_t word = wbT[(size_t)w * Hpad + jc * 64 + lane];
  uint64_t mym = 0;
#pragma unroll
  for (int e = 0; e < 64; ++e) {
    unsigned long long m = __ballot((word >> e) & 1ull);
    mym = (lane == e) ? m : mym;
  }
  int d = w * 64 + lane;
  wt32[(size_t)(jc * 2) * Dpad + d] = (uint32_t)mym;
  wt32[(size_t)(jc * 2 + 1) * Dpad + d] = (uint32_t)(mym >> 32);
}

// fwT[j][l] = sigmoid(2 * cw[l][j]), padded to 64 cols (pad = 0).
__global__ void k_pack_fwT(const float* __restrict__ cw, float* __restrict__ fwT) {
  int idx = blockIdx.x * blockDim.x + threadIdx.x;
  if (idx >= Hn * 64) return;
  int j = idx >> 6, l = idx & 63;
  float v = 0.0f;
  if (l < Ln) {
    float t = 2.0f * cw[(size_t)l * Hn + j];
    v = 1.0f / (1.0f + expf(-t));
  }
  fwT[idx] = v;
}

__global__ void k_zero(float* __restrict__ p, int n) {
  int i = blockIdx.x * blockDim.x + threadIdx.x;
  if (i < n) p[i] = 0.0f;
}

// Encoder (best-measured R7 structure): wave = 256 batch rows (4/lane) x 8 j.
// Per w2-iter: 4 coalesced dwordx4 x-loads + 8 broadcast ds_read_b128 + 256 VALU
// popcount MACs.
__global__ __launch_bounds__(256) void k_enc(const uint64_t* __restrict__ xb2,
                                             const uint64_t* __restrict__ wbT,
                                             const float* __restrict__ b_enc,
                                             const float* __restrict__ act0b,
                                             float* __restrict__ z_out,
                                             uint8_t* __restrict__ zb8) {
  __shared__ uint64_t wl[XW][8];  // 5120 B
  int tid = (int)threadIdx.x;
  int jg = (int)blockIdx.x;  // 0..255: j-group of 8
  int j0 = jg << 3;
#pragma unroll
  for (int k = 0; k < 3; ++k) {
    int idx = k * 256 + tid;
    if (idx < XW * 8) {
      int w = idx >> 3, j = idx & 7;
      wl[w][j] = wbT[(size_t)w * Hpad + j0 + j];
    }
  }
  __syncthreads();

  int wv = __builtin_amdgcn_readfirstlane(tid >> 6);
  int lane = tid & 63;
  int bg = (int)blockIdx.y * 4 + wv;  // 0..15: batch group of 256
  int b0 = (bg << 8) + lane;

  int acc[4][8] = {};
  const uint64_t* xp = xb2 + 2 * (size_t)b0;
#pragma unroll 1
  for (int w2 = 0; w2 < XW / 2; ++w2) {
    ulong2 xx[4];
#pragma unroll
    for (int i = 0; i < 4; ++i)
      xx[i] = *(const ulong2*)(xp + ((size_t)w2 * Bn + i * 64) * 2);
#pragma unroll
    for (int t2 = 0; t2 < 4; ++t2) {
      ulong2 wa = *(ulong2*)&wl[2 * w2][2 * t2];      // broadcast ds_read_b128
      ulong2 wb = *(ulong2*)&wl[2 * w2 + 1][2 * t2];  // broadcast ds_read_b128
#pragma unroll
      for (int i = 0; i < 4; ++i) {
        acc[i][2 * t2]     = popc_acc(xx[i].x & wa.x, acc[i][2 * t2]);
        acc[i][2 * t2 + 1] = popc_acc(xx[i].x & wa.y, acc[i][2 * t2 + 1]);
        acc[i][2 * t2]     = popc_acc(xx[i].y & wb.x, acc[i][2 * t2]);
        acc[i][2 * t2 + 1] = popc_acc(xx[i].y & wb.y, acc[i][2 * t2 + 1]);
      }
    }
  }

  float be[8], ab[8];
#pragma unroll
  for (int t = 0; t < 8; ++t) {
    int j = j0 + t;
    int js = (j < Hn) ? j : (Hn - 1);
    be[t] = b_enc[js];
    ab[t] = act0b[js];
  }
#pragma unroll
  for (int i = 0; i < 4; ++i) {
    int b = b0 + i * 64;
    uint32_t zbyte = 0;
    float zf[8];
#pragma unroll
    for (int t = 0; t < 8; ++t) {
      int j = j0 + t;
      // exact: integer-valued acc + b_enc, then + act0_bias (reference order)
      float h = ((float)acc[i][t] + be[t]) + ab[t];
      bool zb = (j < Hn) && (h >= 1.0f);
      zbyte |= zb ? (1u << t) : 0u;
      zf[t] = zb ? 1.0f : 0.0f;
    }
    // byte (jg&3) of u32 word hw = jg>>2 in [hw][Bn] layout (little-endian match)
    zb8[((size_t)(jg >> 2) * Bn + b) * 4 + (jg & 3)] = (uint8_t)zbyte;
    if (j0 < Hn) {  // 2000 % 8 == 0: group fully valid or fully padded
      float* zp = z_out + (size_t)b * Hn + j0;
      *(float4*)zp = make_float4(zf[0], zf[1], zf[2], zf[3]);
      *(float4*)(zp + 4) = make_float4(zf[4], zf[5], zf[6], zf[7]);
    }
  }
}

// Decoder: wave = 256 batch rows (4 per lane) x 8 outputs, 2-deep pipelined
// (best-measured R10 structure).
__global__ __launch_bounds__(256, 6) void k_dec(const uint32_t* __restrict__ zb32,
                                                const uint32_t* __restrict__ wt32,
                                                const float* __restrict__ act3b,
                                                float* __restrict__ out) {
  __shared__ uint32_t tl[64][8];  // 2048 B
  int tid = (int)threadIdx.x;
  int dc = (int)blockIdx.x;  // 0..639: d-chunk of 8
  int d0 = dc << 3;
  {
#pragma unroll
    for (int k = 0; k < 2; ++k) {
      int e = k * 256 + tid;
      int hw = e >> 3, dl = e & 7;
      tl[hw][dl] = wt32[(size_t)hw * Dpad + d0 + dl];
    }
  }
  __syncthreads();

  int wv = __builtin_amdgcn_readfirstlane(tid >> 6);
  int lane = tid & 63;
  int bg = (int)blockIdx.y * 4 + wv;  // 0..15: batch group of 256
  int b0 = (bg << 8) + lane;

  int acc[4][8] = {};
  const uint32_t* zp = zb32 + b0;

  uint32_t z0, z1, z2, z3, n0, n1, n2, n3;
  uint4 wA, wB, wAn, wBn;
  z0 = zp[0];
  z1 = zp[64];
  z2 = zp[128];
  z3 = zp[192];
  wA = *(const uint4*)&tl[0][0];
  wB = *(const uint4*)&tl[0][4];

#define DEC_MAC()                                       \
  do {                                                  \
    acc[0][0] = __builtin_popcount(z0 & wA.x) + acc[0][0]; \
    acc[0][1] = __builtin_popcount(z0 & wA.y) + acc[0][1]; \
    acc[0][2] = __builtin_popcount(z0 & wA.z) + acc[0][2]; \
    acc[0][3] = __builtin_popcount(z0 & wA.w) + acc[0][3]; \
    acc[0][4] = __builtin_popcount(z0 & wB.x) + acc[0][4]; \
    acc[0][5] = __builtin_popcount(z0 & wB.y) + acc[0][5]; \
    acc[0][6] = __builtin_popcount(z0 & wB.z) + acc[0][6]; \
    acc[0][7] = __builtin_popcount(z0 & wB.w) + acc[0][7]; \
    acc[1][0] = __builtin_popcount(z1 & wA.x) + acc[1][0]; \
    acc[1][1] = __builtin_popcount(z1 & wA.y) + acc[1][1]; \
    acc[1][2] = __builtin_popcount(z1 & wA.z) + acc[1][2]; \
    acc[1][3] = __builtin_popcount(z1 & wA.w) + acc[1][3]; \
    acc[1][4] = __builtin_popcount(z1 & wB.x) + acc[1][4]; \
    acc[1][5] = __builtin_popcount(z1 & wB.y) + acc[1][5]; \
    acc[1][6] = __builtin_popcount(z1 & wB.z) + acc[1][6]; \
    acc[1][7] = __builtin_popcount(z1 & wB.w) + acc[1][7]; \
    acc[2][0] = __builtin_popcount(z2 & wA.x) + acc[2][0]; \
    acc[2][1] = __builtin_popcount(z2 & wA.y) + acc[2][1]; \
    acc[2][2] = __builtin_popcount(z2 & wA.z) + acc[2][2]; \
    acc[2][3] = __builtin_popcount(z2 & wA.w) + acc[2][3]; \
    acc[2][4] = __builtin_popcount(z2 & wB.x) + acc[2][4]; \
    acc[2][5] = __builtin_popcount(z2 & wB.y) + acc[2][5]; \
    acc[2][6] = __builtin_popcount(z2 & wB.z) + acc[2][6]; \
    acc[2][7] = __builtin_popcount(z2 & wB.w) + acc[2][7]; \
    acc[3][0] = __builtin_popcount(z3 & wA.x) + acc[3][0]; \
    acc[3][1] = __builtin_popcount(z3 & wA.y) + acc[3][1]; \
    acc[3][2] = __builtin_popcount(z3 & wA.z) + acc[3][2]; \
    acc[3][3] = __builtin_popcount(z3 & wA.w) + acc[3][3]; \
    acc[3][4] = __builtin_popcount(z3 & wB.x) + acc[3][4]; \
    acc[3][5] = __builtin_popcount(z3 & wB.y) + acc[3][5]; \
    acc[3][6] = __builtin_popcount(z3 & wB.z) + acc[3][6]; \
    acc[3][7] = __builtin_popcount(z3 & wB.w) + acc[3][7]; \
  } while (0)

#pragma unroll 1
  for (int hw = 0; hw < 64; ++hw) {
    int hn = (hw < 63) ? hw + 1 : hw;  // clamped: last iter re-reads
    const uint32_t* zq = zp + (size_t)hn * Bn;
    n0 = zq[0];
    n1 = zq[64];
    n2 = zq[128];
    n3 = zq[192];
    wAn = *(const uint4*)&tl[hn][0];
    wBn = *(const uint4*)&tl[hn][4];
    DEC_MAC();
    z0 = n0; z1 = n1; z2 = n2; z3 = n3;
    wA = wAn; wB = wBn;
  }
#undef DEC_MAC

  float ab[8];
#pragma unroll
  for (int t = 0; t < 8; ++t) {
    int d = d0 + t;
    int ds = (d < Dn) ? d : (Dn - 1);
    ab[t] = act3b[ds];
  }
  if (d0 < Dn) {  // 5000 % 8 == 0: chunk fully valid or fully padded
#pragma unroll
    for (int i = 0; i < 4; ++i) {
      int b = b0 + i * 64;
      float of[8];
#pragma unroll
      for (int t = 0; t < 8; ++t)
        of[t] = (((float)acc[i][t] + ab[t]) >= 1.0f) ? 1.0f : 0.0f;
      float* op = out + (size_t)b * Dn + d0;
      *(float4*)op = make_float4(of[0], of[1], of[2], of[3]);
      *(float4*)(op + 4) = make_float4(of[4], of[5], of[6], of[7]);
    }
  }
}

// classification = z @ fwT: LDS-tiled outer-product GEMM.
// Block = 128 b-rows x 64 l x 256 j-slice (4 tiles of 64 j). Thread = 8b x 4l.
__global__ __launch_bounds__(256) void k_cls(const float* __restrict__ z,
                                             const float* __restrict__ fwT,
                                             float* __restrict__ cls) {
  __shared__ float zT[64][132];   // transposed z tile, padded stride
  __shared__ float fwL[64][64];   // fw tile
  int tid = (int)threadIdx.x;
  int bb0 = (int)blockIdx.x * 128;
  int jsp = (int)blockIdx.y;      // 0..7
  int tx = tid & 15, ty = tid >> 4;
  float acc[8][4] = {};

  for (int tile = 0; tile < 4; ++tile) {
    int jt0 = jsp * 256 + tile * 64;
    __syncthreads();
#pragma unroll
    for (int k = 0; k < 8; ++k) {
      int idx = k * 256 + tid;
      int r = idx >> 4, c4 = idx & 15;
      int j = jt0 + c4 * 4;
      float4 v = make_float4(0.f, 0.f, 0.f, 0.f);
      if (j < Hn) v = *(const float4*)(z + (size_t)(bb0 + r) * Hn + j);
      zT[c4 * 4 + 0][r] = v.x;
      zT[c4 * 4 + 1][r] = v.y;
      zT[c4 * 4 + 2][r] = v.z;
      zT[c4 * 4 + 3][r] = v.w;
    }
#pragma unroll
    for (int k = 0; k < 4; ++k) {
      int idx = k * 256 + tid;
      int jj = idx >> 4, c4 = idx & 15;
      int j = jt0 + jj;
      float4 v = make_float4(0.f, 0.f, 0.f, 0.f);
      if (j < Hn) v = *(const float4*)(fwT + (size_t)j * 64 + c4 * 4);
      *(float4*)&fwL[jj][c4 * 4] = v;
    }
    __syncthreads();
#pragma unroll 4
    for (int jj = 0; jj < 64; ++jj) {
      float4 fv = *(float4*)&fwL[jj][tx * 4];
      float4 za = *(float4*)&zT[jj][ty * 8];
      float4 zb = *(float4*)&zT[jj][ty * 8 + 4];
      float zz[8] = {za.x, za.y, za.z, za.w, zb.x, zb.y, zb.z, zb.w};
      float ff[4] = {fv.x, fv.y, fv.z, fv.w};
#pragma unroll
      for (int i = 0; i < 8; ++i)
#pragma unroll
        for (int l = 0; l < 4; ++l) acc[i][l] += zz[i] * ff[l];
    }
  }

#pragma unroll
  for (int i = 0; i < 8; ++i) {
    int b = bb0 + ty * 8 + i;
#pragma unroll
    for (int l = 0; l < 4; ++l) {
      int L = tx * 4 + l;
      if (L < Ln) atomicAdd(&cls[(size_t)b * Ln + L], acc[i][l]);
    }
  }
}

extern "C" void kernel_launch(void* const* d_in, const int* in_sizes, int n_in,
                              void* d_out, int out_size, void* d_ws, size_t ws_size,
                              hipStream_t stream) {
  const float* x     = (const float*)d_in[0];  // [B][D]
  const float* W     = (const float*)d_in[1];  // [H][D]
  const float* b_enc = (const float*)d_in[2];  // [H]
  const float* act0b = (const float*)d_in[3];  // [H]
  const float* act3b = (const float*)d_in[4];  // [D]
  const float* cw    = (const float*)d_in[5];  // [L][H]

  float* out0 = (float*)d_out;              // output        [B][D]
  float* cls  = out0 + (size_t)Bn * Dn;     // classification[B][L]
  float* zout = cls + (size_t)Bn * Ln;      // z             [B][H]

  // Workspace (~6.8 MB).
  char* ws = (char*)d_ws;
  uint64_t* xb2  = (uint64_t*)ws; ws += (size_t)XW * Bn * 8;    // 2.62 MB [40][Bn][2]
  uint64_t* wbT  = (uint64_t*)ws; ws += (size_t)XW * Hpad * 8;  // 1.31 MB [80][Hpad]
  uint32_t* wt32 = (uint32_t*)ws; ws += (size_t)64 * Dpad * 4;  // 1.31 MB [64][Dpad]
  uint32_t* zb32 = (uint32_t*)ws; ws += (size_t)64 * Bn * 4;    // 1.05 MB [64][Bn] u32 (byte-assembled)
  float*    fwT  = (float*)ws;    ws += (size_t)Hn * 64 * 4;    // 0.51 MB

  {  // x -> xb2 (paired word-major transpose)
    long long waves = (long long)Bn * (XW / 4);
    k_pack_x<<<(int)((waves * 64 + 255) / 256), 256, 0, stream>>>(x, xb2);
  }
  {  // W -> wbT (ballot-only, memory-bound)
    long long waves = (long long)Hn * (XW / 4);
    k_pack_w<<<(int)((waves * 64 + 255) / 256), 256, 0, stream>>>(W, wbT);
  }
  {  // wbT -> wt32 (cross-lane bit transpose)
    long long waves = (long long)(Hpad / 64) * XW;  // 32*80 = 2560
    k_transp<<<(int)((waves * 64 + 255) / 256), 256, 0, stream>>>(wbT, wt32);
  }
  k_pack_fwT<<<(Hn * 64 + 255) / 256, 256, 0, stream>>>(cw, fwT);
  k_zero<<<(Bn * Ln + 255) / 256, 256, 0, stream>>>(cls, Bn * Ln);

  // enc: 256 j-groups x 16 batch groups (4 waves/block) = 4096 waves
  dim3 g1(256, 4);
  k_enc<<<g1, 256, 0, stream>>>(xb2, wbT, b_enc, act0b, zout, (uint8_t*)zb32);

  // cls: 32 b-blocks x 8 j-splits = 256 blocks
  dim3 g3(32, 8);
  k_cls<<<g3, 256, 0, stream>>>(zout, fwT, cls);

  // dec: 640 d-chunks x 16 batch groups (4 waves/block) = 10240 waves
  dim3 g2(640, 4);
  k_dec<<<g2, 256, 0, stream>>>(zb32, wt32, act3b, out0);
}

// Round 12
// 248.856 us; speedup vs baseline: 1.5078x; 1.1650x over previous
//
#include <hip/hip_runtime.h>
#include <stdint.h>

// Problem sizes.
static constexpr int Bn = 4096;
static constexpr int Dn = 5000;
static constexpr int Hn = 2000;
static constexpr int Ln = 50;
static constexpr int XW = 80;      // u64 words covering D (5120 bits)
static constexpr int Hpad = 2048;  // padded H (N for enc GEMM)
static constexpr int Dpad = 5120;  // padded D (K for enc GEMM)

typedef int v4i __attribute__((ext_vector_type(4)));
typedef int v16i __attribute__((ext_vector_type(16)));

__device__ __forceinline__ int popc_acc(uint64_t v, int acc) {
  acc = __builtin_popcount((uint32_t)v) + acc;
  acc = __builtin_popcount((uint32_t)(v >> 32)) + acc;
  return acc;
}

// ---------- i8 packing for the MFMA encoder ----------
// dst[row][col] = (src[row][col] >= 0.5) as i8, zero-padded to [nrows_out][5120].
__global__ void k_pack_i8(const float* __restrict__ src, uint8_t* __restrict__ dst,
                          int nrows_out, int nrows_valid, int ncols_src) {
  int g = (int)blockIdx.x * 256 + (int)threadIdx.x;
  int row = g / (Dpad / 4);
  int c4 = g - row * (Dpad / 4);
  if (row >= nrows_out) return;
  int col = c4 * 4;
  uchar4 o = make_uchar4(0, 0, 0, 0);
  if (row < nrows_valid && col + 3 < ncols_src) {
    const float4 v = *(const float4*)(src + (size_t)row * ncols_src + col);
    o.x = v.x >= 0.5f; o.y = v.y >= 0.5f; o.z = v.z >= 0.5f; o.w = v.w >= 0.5f;
  }
  *(uchar4*)(dst + (size_t)row * Dpad + col) = o;
}

// ---------- bit packing (kept for decoder + fallback) ----------
__global__ void k_pack_x(const float* __restrict__ x, uint64_t* __restrict__ xb2) {
  int g = (int)((blockIdx.x * blockDim.x + threadIdx.x) >> 6);
  int lane = (int)(threadIdx.x & 63);
  constexpr int nq = XW >> 2;
  int row = g / nq;
  int q = g - row * nq;
  if (row >= Bn) return;
  int w0 = q << 2;
  unsigned long long m[4];
#pragma unroll
  for (int e = 0; e < 4; ++e) {
    int col = ((w0 + e) << 6) + lane;
    float v = (col < Dn) ? x[(size_t)row * Dn + col] : 0.0f;
    m[e] = __ballot(v >= 0.5f);
  }
  if (lane < 4) {
    unsigned long long mv = m[0];
    mv = (lane == 1) ? m[1] : mv;
    mv = (lane == 2) ? m[2] : mv;
    mv = (lane == 3) ? m[3] : mv;
    int w = w0 + lane;
    xb2[((size_t)(w >> 1) * Bn + row) * 2 + (w & 1)] = mv;
  }
}

__global__ void k_pack_w(const float* __restrict__ W, uint64_t* __restrict__ wbT) {
  int g = (int)((blockIdx.x * blockDim.x + threadIdx.x) >> 6);
  int lane = (int)(threadIdx.x & 63);
  constexpr int nq = XW >> 2;
  int row = g / nq;
  int q = g - row * nq;
  if (row >= Hn) return;
  int w0 = q << 2;
  unsigned long long m[4];
#pragma unroll
  for (int e = 0; e < 4; ++e) {
    int col = ((w0 + e) << 6) + lane;
    float v = (col < Dn) ? W[(size_t)row * Dn + col] : 0.0f;
    m[e] = __ballot(v >= 0.5f);
  }
  if (lane < 4) {
    unsigned long long mv = m[0];
    mv = (lane == 1) ? m[1] : mv;
    mv = (lane == 2) ? m[2] : mv;
    mv = (lane == 3) ? m[3] : mv;
    wbT[(size_t)(w0 + lane) * Hpad + row] = mv;
  }
}

__global__ void k_transp(const uint64_t* __restrict__ wbT, uint32_t* __restrict__ wt32) {
  int g = (int)((blockIdx.x * blockDim.x + threadIdx.x) >> 6);
  int lane = (int)(threadIdx.x & 63);
  int w = g % XW;
  int jc = g / XW;
  if (jc >= Hpad / 64) return;
  uint64_t word = wbT[(size_t)w * Hpad + jc * 64 + lane];
  uint64_t mym = 0;
#pragma unroll
  for (int e = 0; e < 64; ++e) {
    unsigned long long m = __ballot((word >> e) & 1ull);
    mym = (lane == e) ? m : mym;
  }
  int d = w * 64 + lane;
  wt32[(size_t)(jc * 2) * Dpad + d] = (uint32_t)mym;
  wt32[(size_t)(jc * 2 + 1) * Dpad + d] = (uint32_t)(mym >> 32);
}

__global__ void k_pack_fwT(const float* __restrict__ cw, float* __restrict__ fwT) {
  int idx = blockIdx.x * blockDim.x + threadIdx.x;
  if (idx >= Hn * 64) return;
  int j = idx >> 6, l = idx & 63;
  float v = 0.0f;
  if (l < Ln) {
    float t = 2.0f * cw[(size_t)l * Hn + j];
    v = 1.0f / (1.0f + expf(-t));
  }
  fwT[idx] = v;
}

__global__ void k_zero(float* __restrict__ p, int n) {
  int i = blockIdx.x * blockDim.x + threadIdx.x;
  if (i < n) p[i] = 0.0f;
}

// ---------- MFMA encoder ----------
// h = xi8 @ wi8^T (exact i32), z = (h + b_enc + act0b >= 1).
// Block: 128x128 tile, 4 waves (2x2 of 64x64), BK=128 bytes, 40 K-iters.
// LDS XOR-swizzle (row&7)<<4 on 16B slots; reg-staged (load->ds_write).
// C/D layout (m101): col=lane&31, row=(reg&3)+8*(reg>>2)+4*(lane>>5).
__global__ __launch_bounds__(256) void k_enc_mfma(
    const uint8_t* __restrict__ A,   // xi8 [4096][5120]
    const uint8_t* __restrict__ B,   // wi8 [2048][5120]
    const float* __restrict__ b_enc, const float* __restrict__ act0b,
    float* __restrict__ z_out, uint32_t* __restrict__ zb32) {
  __shared__ uint8_t As[128 * 128];
  __shared__ uint8_t Bs[128 * 128];
  int tid = (int)threadIdx.x;
  int bn = (int)blockIdx.x;  // 0..15 (N tiles)
  int bm = (int)blockIdx.y;  // 0..31 (M tiles)
  int wv = __builtin_amdgcn_readfirstlane(tid >> 6);
  int lane = tid & 63;
  int wm = wv >> 1, wn = wv & 1;

  v16i acc[2][2];
#pragma unroll
  for (int i = 0; i < 2; ++i)
#pragma unroll
    for (int j = 0; j < 2; ++j) acc[i][j] = (v16i)0;

  // staging: thread covers rows {srow, srow+32, +64, +96}, 16B slot sq
  int srow = tid >> 3;   // 0..31
  int sq = tid & 7;      // 0..7
  int ldsw = srow * 128 + ((sq ^ (srow & 7)) << 4);
  const uint8_t* ap = A + ((size_t)(bm * 128 + srow)) * Dpad + sq * 16;
  const uint8_t* bp = B + ((size_t)(bn * 128 + srow)) * Dpad + sq * 16;

  int arow = wm * 64 + (lane & 31);  // +mi*32
  int brow = wn * 64 + (lane & 31);  // +ni*32
  int khalf = lane >> 5;
  int asw = arow & 7;  // (arow+32)&7 == arow&7
  int bsw = brow & 7;

#pragma unroll 1
  for (int kt = 0; kt < 40; ++kt) {
    int k0 = kt * 128;
    v4i ra[4], rb[4];
#pragma unroll
    for (int i = 0; i < 4; ++i) {
      ra[i] = *(const v4i*)(ap + k0 + (size_t)i * 32 * Dpad);
      rb[i] = *(const v4i*)(bp + k0 + (size_t)i * 32 * Dpad);
    }
    __syncthreads();  // previous compute done before overwrite
#pragma unroll
    for (int i = 0; i < 4; ++i) {
      *(v4i*)(As + i * 4096 + ldsw) = ra[i];
      *(v4i*)(Bs + i * 4096 + ldsw) = rb[i];
    }
    __syncthreads();
#pragma unroll
    for (int kk = 0; kk < 4; ++kk) {
      int kq = kk * 2 + khalf;
      v4i a0 = *(const v4i*)(As + arow * 128 + ((kq ^ asw) << 4));
      v4i a1 = *(const v4i*)(As + (arow + 32) * 128 + ((kq ^ asw) << 4));
      v4i b0 = *(const v4i*)(Bs + brow * 128 + ((kq ^ bsw) << 4));
      v4i b1 = *(const v4i*)(Bs + (brow + 32) * 128 + ((kq ^ bsw) << 4));
      acc[0][0] = __builtin_amdgcn_mfma_i32_32x32x32_i8(a0, b0, acc[0][0], 0, 0, 0);
      acc[0][1] = __builtin_amdgcn_mfma_i32_32x32x32_i8(a0, b1, acc[0][1], 0, 0, 0);
      acc[1][0] = __builtin_amdgcn_mfma_i32_32x32x32_i8(a1, b0, acc[1][0], 0, 0, 0);
      acc[1][1] = __builtin_amdgcn_mfma_i32_32x32x32_i8(a1, b1, acc[1][1], 0, 0, 0);
    }
  }

  // epilogue: bias + threshold, write z floats + zb32 ballot bits
  int col0 = bn * 128 + wn * 64 + (lane & 31);
#pragma unroll
  for (int ni = 0; ni < 2; ++ni) {
    int j = col0 + ni * 32;
    int js = (j < Hn) ? j : (Hn - 1);
    float be = b_enc[js];
    float ab = act0b[js];
    bool jv = j < Hn;
    int hw = (bn * 128 + wn * 64 + ni * 32) >> 5;
#pragma unroll
    for (int mi = 0; mi < 2; ++mi) {
      int rbase = bm * 128 + wm * 64 + mi * 32;
#pragma unroll
      for (int r = 0; r < 16; ++r) {
        int rloc = (r & 3) + 8 * (r >> 2) + 4 * (lane >> 5);
        int b = rbase + rloc;
        // exact: integer-valued acc + b_enc, then + act0_bias (reference order)
        float h = ((float)acc[mi][ni][r] + be) + ab;
        bool zb = jv && (h >= 1.0f);
        if (jv) z_out[(size_t)b * Hn + j] = zb ? 1.0f : 0.0f;
        unsigned long long m = __ballot(zb);
        if (lane == 0) {
          int blo = rbase + (r & 3) + 8 * (r >> 2);
          zb32[(size_t)hw * Bn + blo] = (uint32_t)m;
          zb32[(size_t)hw * Bn + blo + 4] = (uint32_t)(m >> 32);
        }
      }
    }
  }
}

// ---------- fallback bit encoder (R11) ----------
__global__ __launch_bounds__(256) void k_enc_bit(const uint64_t* __restrict__ xb2,
                                                 const uint64_t* __restrict__ wbT,
                                                 const float* __restrict__ b_enc,
                                                 const float* __restrict__ act0b,
                                                 float* __restrict__ z_out,
                                                 uint8_t* __restrict__ zb8) {
  __shared__ uint64_t wl[XW][8];
  int tid = (int)threadIdx.x;
  int jg = (int)blockIdx.x;
  int j0 = jg << 3;
#pragma unroll
  for (int k = 0; k < 3; ++k) {
    int idx = k * 256 + tid;
    if (idx < XW * 8) {
      int w = idx >> 3, j = idx & 7;
      wl[w][j] = wbT[(size_t)w * Hpad + j0 + j];
    }
  }
  __syncthreads();
  int wv = __builtin_amdgcn_readfirstlane(tid >> 6);
  int lane = tid & 63;
  int bg = (int)blockIdx.y * 4 + wv;
  int b0 = (bg << 8) + lane;
  int acc[4][8] = {};
  const uint64_t* xp = xb2 + 2 * (size_t)b0;
#pragma unroll 1
  for (int w2 = 0; w2 < XW / 2; ++w2) {
    ulong2 xx[4];
#pragma unroll
    for (int i = 0; i < 4; ++i)
      xx[i] = *(const ulong2*)(xp + ((size_t)w2 * Bn + i * 64) * 2);
#pragma unroll
    for (int t2 = 0; t2 < 4; ++t2) {
      ulong2 wa = *(ulong2*)&wl[2 * w2][2 * t2];
      ulong2 wb = *(ulong2*)&wl[2 * w2 + 1][2 * t2];
#pragma unroll
      for (int i = 0; i < 4; ++i) {
        acc[i][2 * t2]     = popc_acc(xx[i].x & wa.x, acc[i][2 * t2]);
        acc[i][2 * t2 + 1] = popc_acc(xx[i].x & wa.y, acc[i][2 * t2 + 1]);
        acc[i][2 * t2]     = popc_acc(xx[i].y & wb.x, acc[i][2 * t2]);
        acc[i][2 * t2 + 1] = popc_acc(xx[i].y & wb.y, acc[i][2 * t2 + 1]);
      }
    }
  }
  float be[8], ab[8];
#pragma unroll
  for (int t = 0; t < 8; ++t) {
    int j = j0 + t;
    int js = (j < Hn) ? j : (Hn - 1);
    be[t] = b_enc[js];
    ab[t] = act0b[js];
  }
#pragma unroll
  for (int i = 0; i < 4; ++i) {
    int b = b0 + i * 64;
    uint32_t zbyte = 0;
    float zf[8];
#pragma unroll
    for (int t = 0; t < 8; ++t) {
      int j = j0 + t;
      float h = ((float)acc[i][t] + be[t]) + ab[t];
      bool zb = (j < Hn) && (h >= 1.0f);
      zbyte |= zb ? (1u << t) : 0u;
      zf[t] = zb ? 1.0f : 0.0f;
    }
    zb8[((size_t)(jg >> 2) * Bn + b) * 4 + (jg & 3)] = (uint8_t)zbyte;
    if (j0 < Hn) {
      float* zp = z_out + (size_t)b * Hn + j0;
      *(float4*)zp = make_float4(zf[0], zf[1], zf[2], zf[3]);
      *(float4*)(zp + 4) = make_float4(zf[4], zf[5], zf[6], zf[7]);
    }
  }
}

// ---------- decoder (R10 2-deep pipelined, unchanged) ----------
__global__ __launch_bounds__(256, 6) void k_dec(const uint32_t* __restrict__ zb32,
                                                const uint32_t* __restrict__ wt32,
                                                const float* __restrict__ act3b,
                                                float* __restrict__ out) {
  __shared__ uint32_t tl[64][8];
  int tid = (int)threadIdx.x;
  int dc = (int)blockIdx.x;
  int d0 = dc << 3;
  {
#pragma unroll
    for (int k = 0; k < 2; ++k) {
      int e = k * 256 + tid;
      int hw = e >> 3, dl = e & 7;
      tl[hw][dl] = wt32[(size_t)hw * Dpad + d0 + dl];
    }
  }
  __syncthreads();
  int wv = __builtin_amdgcn_readfirstlane(tid >> 6);
  int lane = tid & 63;
  int bg = (int)blockIdx.y * 4 + wv;
  int b0 = (bg << 8) + lane;
  int acc[4][8] = {};
  const uint32_t* zp = zb32 + b0;
  uint32_t z0, z1, z2, z3, n0, n1, n2, n3;
  uint4 wA, wB, wAn, wBn;
  z0 = zp[0]; z1 = zp[64]; z2 = zp[128]; z3 = zp[192];
  wA = *(const uint4*)&tl[0][0];
  wB = *(const uint4*)&tl[0][4];
#define DEC_MAC()                                          \
  do {                                                     \
    acc[0][0] = __builtin_popcount(z0 & wA.x) + acc[0][0]; \
    acc[0][1] = __builtin_popcount(z0 & wA.y) + acc[0][1]; \
    acc[0][2] = __builtin_popcount(z0 & wA.z) + acc[0][2]; \
    acc[0][3] = __builtin_popcount(z0 & wA.w) + acc[0][3]; \
    acc[0][4] = __builtin_popcount(z0 & wB.x) + acc[0][4]; \
    acc[0][5] = __builtin_popcount(z0 & wB.y) + acc[0][5]; \
    acc[0][6] = __builtin_popcount(z0 & wB.z) + acc[0][6]; \
    acc[0][7] = __builtin_popcount(z0 & wB.w) + acc[0][7]; \
    acc[1][0] = __builtin_popcount(z1 & wA.x) + acc[1][0]; \
    acc[1][1] = __builtin_popcount(z1 & wA.y) + acc[1][1]; \
    acc[1][2] = __builtin_popcount(z1 & wA.z) + acc[1][2]; \
    acc[1][3] = __builtin_popcount(z1 & wA.w) + acc[1][3]; \
    acc[1][4] = __builtin_popcount(z1 & wB.x) + acc[1][4]; \
    acc[1][5] = __builtin_popcount(z1 & wB.y) + acc[1][5]; \
    acc[1][6] = __builtin_popcount(z1 & wB.z) + acc[1][6]; \
    acc[1][7] = __builtin_popcount(z1 & wB.w) + acc[1][7]; \
    acc[2][0] = __builtin_popcount(z2 & wA.x) + acc[2][0]; \
    acc[2][1] = __builtin_popcount(z2 & wA.y) + acc[2][1]; \
    acc[2][2] = __builtin_popcount(z2 & wA.z) + acc[2][2]; \
    acc[2][3] = __builtin_popcount(z2 & wA.w) + acc[2][3]; \
    acc[2][4] = __builtin_popcount(z2 & wB.x) + acc[2][4]; \
    acc[2][5] = __builtin_popcount(z2 & wB.y) + acc[2][5]; \
    acc[2][6] = __builtin_popcount(z2 & wB.z) + acc[2][6]; \
    acc[2][7] = __builtin_popcount(z2 & wB.w) + acc[2][7]; \
    acc[3][0] = __builtin_popcount(z3 & wA.x) + acc[3][0]; \
    acc[3][1] = __builtin_popcount(z3 & wA.y) + acc[3][1]; \
    acc[3][2] = __builtin_popcount(z3 & wA.z) + acc[3][2]; \
    acc[3][3] = __builtin_popcount(z3 & wA.w) + acc[3][3]; \
    acc[3][4] = __builtin_popcount(z3 & wB.x) + acc[3][4]; \
    acc[3][5] = __builtin_popcount(z3 & wB.y) + acc[3][5]; \
    acc[3][6] = __builtin_popcount(z3 & wB.z) + acc[3][6]; \
    acc[3][7] = __builtin_popcount(z3 & wB.w) + acc[3][7]; \
  } while (0)
#pragma unroll 1
  for (int hw = 0; hw < 64; ++hw) {
    int hn = (hw < 63) ? hw + 1 : hw;
    const uint32_t* zq = zp + (size_t)hn * Bn;
    n0 = zq[0]; n1 = zq[64]; n2 = zq[128]; n3 = zq[192];
    wAn = *(const uint4*)&tl[hn][0];
    wBn = *(const uint4*)&tl[hn][4];
    DEC_MAC();
    z0 = n0; z1 = n1; z2 = n2; z3 = n3;
    wA = wAn; wB = wBn;
  }
#undef DEC_MAC
  float ab[8];
#pragma unroll
  for (int t = 0; t < 8; ++t) {
    int d = d0 + t;
    int ds = (d < Dn) ? d : (Dn - 1);
    ab[t] = act3b[ds];
  }
  if (d0 < Dn) {
#pragma unroll
    for (int i = 0; i < 4; ++i) {
      int b = b0 + i * 64;
      float of[8];
#pragma unroll
      for (int t = 0; t < 8; ++t)
        of[t] = (((float)acc[i][t] + ab[t]) >= 1.0f) ? 1.0f : 0.0f;
      float* op = out + (size_t)b * Dn + d0;
      *(float4*)op = make_float4(of[0], of[1], of[2], of[3]);
      *(float4*)(op + 4) = make_float4(of[4], of[5], of[6], of[7]);
    }
  }
}

// ---------- classifier GEMM (unchanged) ----------
__global__ __launch_bounds__(256) void k_cls(const float* __restrict__ z,
                                             const float* __restrict__ fwT,
                                             float* __restrict__ cls) {
  __shared__ float zT[64][132];
  __shared__ float fwL[64][64];
  int tid = (int)threadIdx.x;
  int bb0 = (int)blockIdx.x * 128;
  int jsp = (int)blockIdx.y;
  int tx = tid & 15, ty = tid >> 4;
  float acc[8][4] = {};
  for (int tile = 0; tile < 4; ++tile) {
    int jt0 = jsp * 256 + tile * 64;
    __syncthreads();
#pragma unroll
    for (int k = 0; k < 8; ++k) {
      int idx = k * 256 + tid;
      int r = idx >> 4, c4 = idx & 15;
      int j = jt0 + c4 * 4;
      float4 v = make_float4(0.f, 0.f, 0.f, 0.f);
      if (j < Hn) v = *(const float4*)(z + (size_t)(bb0 + r) * Hn + j);
      zT[c4 * 4 + 0][r] = v.x;
      zT[c4 * 4 + 1][r] = v.y;
      zT[c4 * 4 + 2][r] = v.z;
      zT[c4 * 4 + 3][r] = v.w;
    }
#pragma unroll
    for (int k = 0; k < 4; ++k) {
      int idx = k * 256 + tid;
      int jj = idx >> 4, c4 = idx & 15;
      int j = jt0 + jj;
      float4 v = make_float4(0.f, 0.f, 0.f, 0.f);
      if (j < Hn) v = *(const float4*)(fwT + (size_t)j * 64 + c4 * 4);
      *(float4*)&fwL[jj][c4 * 4] = v;
    }
    __syncthreads();
#pragma unroll 4
    for (int jj = 0; jj < 64; ++jj) {
      float4 fv = *(float4*)&fwL[jj][tx * 4];
      float4 za = *(float4*)&zT[jj][ty * 8];
      float4 zb = *(float4*)&zT[jj][ty * 8 + 4];
      float zz[8] = {za.x, za.y, za.z, za.w, zb.x, zb.y, zb.z, zb.w};
      float ff[4] = {fv.x, fv.y, fv.z, fv.w};
#pragma unroll
      for (int i = 0; i < 8; ++i)
#pragma unroll
        for (int l = 0; l < 4; ++l) acc[i][l] += zz[i] * ff[l];
    }
  }
#pragma unroll
  for (int i = 0; i < 8; ++i) {
    int b = bb0 + ty * 8 + i;
#pragma unroll
    for (int l = 0; l < 4; ++l) {
      int L = tx * 4 + l;
      if (L < Ln) atomicAdd(&cls[(size_t)b * Ln + L], acc[i][l]);
    }
  }
}

extern "C" void kernel_launch(void* const* d_in, const int* in_sizes, int n_in,
                              void* d_out, int out_size, void* d_ws, size_t ws_size,
                              hipStream_t stream) {
  const float* x     = (const float*)d_in[0];
  const float* W     = (const float*)d_in[1];
  const float* b_enc = (const float*)d_in[2];
  const float* act0b = (const float*)d_in[3];
  const float* act3b = (const float*)d_in[4];
  const float* cw    = (const float*)d_in[5];

  float* out0 = (float*)d_out;
  float* cls  = out0 + (size_t)Bn * Dn;
  float* zout = cls + (size_t)Bn * Ln;

  // Common workspace
  char* ws = (char*)d_ws;
  uint64_t* wbT  = (uint64_t*)ws; ws += (size_t)XW * Hpad * 8;  // 1.31 MB
  uint32_t* wt32 = (uint32_t*)ws; ws += (size_t)64 * Dpad * 4;  // 1.31 MB
  uint32_t* zb32 = (uint32_t*)ws; ws += (size_t)64 * Bn * 4;    // 1.05 MB
  float*    fwT  = (float*)ws;    ws += (size_t)Hn * 64 * 4;    // 0.51 MB
  size_t common = (size_t)(ws - (char*)d_ws);
  size_t need_mfma = common + (size_t)Bn * Dpad + (size_t)Hpad * Dpad;  // +31.5 MB
  size_t need_bit = common + (size_t)XW * Bn * 8;                       // +2.62 MB

  {  // W -> wbT (ballot)
    long long waves = (long long)Hn * (XW / 4);
    k_pack_w<<<(int)((waves * 64 + 255) / 256), 256, 0, stream>>>(W, wbT);
  }
  {  // wbT -> wt32
    long long waves = (long long)(Hpad / 64) * XW;
    k_transp<<<(int)((waves * 64 + 255) / 256), 256, 0, stream>>>(wbT, wt32);
  }
  k_pack_fwT<<<(Hn * 64 + 255) / 256, 256, 0, stream>>>(cw, fwT);
  k_zero<<<(Bn * Ln + 255) / 256, 256, 0, stream>>>(cls, Bn * Ln);

  if (ws_size >= need_mfma) {
    uint8_t* xi8 = (uint8_t*)ws;
    uint8_t* wi8 = xi8 + (size_t)Bn * Dpad;
    k_pack_i8<<<(Bn * (Dpad / 4) + 255) / 256, 256, 0, stream>>>(x, xi8, Bn, Bn, Dn);
    k_pack_i8<<<(Hpad * (Dpad / 4) + 255) / 256, 256, 0, stream>>>(W, wi8, Hpad, Hn, Dn);
    dim3 ge(Hpad / 128, Bn / 128);  // (16, 32)
    k_enc_mfma<<<ge, 256, 0, stream>>>(xi8, wi8, b_enc, act0b, zout, zb32);
  } else {
    uint64_t* xb2 = (uint64_t*)ws;
    {
      long long waves = (long long)Bn * (XW / 4);
      k_pack_x<<<(int)((waves * 64 + 255) / 256), 256, 0, stream>>>(x, xb2);
    }
    (void)need_bit;
    dim3 g1(256, 4);
    k_enc_bit<<<g1, 256, 0, stream>>>(xb2, wbT, b_enc, act0b, zout, (uint8_t*)zb32);
  }

  dim3 g3(32, 8);
  k_cls<<<g3, 256, 0, stream>>>(zout, fwT, cls);

  dim3 g2(640, 4);
  k_dec<<<g2, 256, 0, stream>>>(zb32, wt32, act3b, out0);
}

// Round 13
// 238.182 us; speedup vs baseline: 1.5754x; 1.0448x over previous
//
#include <hip/hip_runtime.h>
#include <stdint.h>

// Problem sizes.
static constexpr int Bn = 4096;
static constexpr int Dn = 5000;
static constexpr int Hn = 2000;
static constexpr int Ln = 50;
static constexpr int XW = 80;      // u64 words covering D (5120 bits)
static constexpr int Hpad = 2048;  // padded H
static constexpr int Dpad = 5120;  // padded D

typedef int v4i __attribute__((ext_vector_type(4)));
typedef int v16i __attribute__((ext_vector_type(16)));

__device__ __forceinline__ int popc_acc(uint64_t v, int acc) {
  acc = __builtin_popcount((uint32_t)v) + acc;
  acc = __builtin_popcount((uint32_t)(v >> 32)) + acc;
  return acc;
}

// ---------- packing ----------
// dst[row][col] = (src[row][col] >= 0.5) as i8, zero-padded to [nrows_out][5120].
__global__ void k_pack_i8(const float* __restrict__ src, uint8_t* __restrict__ dst,
                          int nrows_out, int nrows_valid, int ncols_src) {
  int g = (int)blockIdx.x * 256 + (int)threadIdx.x;
  int row = g / (Dpad / 4);
  int c4 = g - row * (Dpad / 4);
  if (row >= nrows_out) return;
  int col = c4 * 4;
  uchar4 o = make_uchar4(0, 0, 0, 0);
  if (row < nrows_valid && col + 3 < ncols_src) {
    const float4 v = *(const float4*)(src + (size_t)row * ncols_src + col);
    o.x = v.x >= 0.5f; o.y = v.y >= 0.5f; o.z = v.z >= 0.5f; o.w = v.w >= 0.5f;
  }
  *(uchar4*)(dst + (size_t)row * Dpad + col) = o;
}

// One coalesced W pass -> wi8[j][d] (i8 rows, enc B) AND wtd[d][j] (i8 transposed,
// dec B). Column bits accumulate in a register u64, then expand to 64 bytes and
// store as 4x16B (all 4 land in the same 64B line -> merged).
__global__ __launch_bounds__(256) void k_pack_w_dual(const float* __restrict__ W,
                                                     uint8_t* __restrict__ wi8,
                                                     uint8_t* __restrict__ wtd) {
  int d = (int)blockIdx.x * 256 + (int)threadIdx.x;  // 0..5119
  int j0 = (int)blockIdx.y * 64;                     // 32 blocks
  bool dv = d < Dn;
  uint64_t colbits = 0;
  for (int r = 0; r < 64; ++r) {
    int j = j0 + r;
    float v = (j < Hn && dv) ? W[(size_t)j * Dn + d] : 0.0f;
    uint8_t bit = (v >= 0.5f) ? 1 : 0;
    wi8[(size_t)j * Dpad + d] = bit;  // coalesced
    colbits |= ((uint64_t)bit) << r;
  }
  uint8_t* dst = wtd + (size_t)d * Hpad + j0;
#pragma unroll
  for (int q = 0; q < 4; ++q) {
    uint32_t u[4];
#pragma unroll
    for (int s = 0; s < 4; ++s) {
      uint32_t nib = (uint32_t)((colbits >> (q * 16 + s * 4)) & 0xFull);
      u[s] = (nib & 1u) | (((nib >> 1) & 1u) << 8) | (((nib >> 2) & 1u) << 16) |
             (((nib >> 3) & 1u) << 24);
    }
    *(uint4*)(dst + q * 16) = make_uint4(u[0], u[1], u[2], u[3]);
  }
}

// ---------- bit packing (fallback tiers) ----------
__global__ void k_pack_x(const float* __restrict__ x, uint64_t* __restrict__ xb2) {
  int g = (int)((blockIdx.x * blockDim.x + threadIdx.x) >> 6);
  int lane = (int)(threadIdx.x & 63);
  constexpr int nq = XW >> 2;
  int row = g / nq;
  int q = g - row * nq;
  if (row >= Bn) return;
  int w0 = q << 2;
  unsigned long long m[4];
#pragma unroll
  for (int e = 0; e < 4; ++e) {
    int col = ((w0 + e) << 6) + lane;
    float v = (col < Dn) ? x[(size_t)row * Dn + col] : 0.0f;
    m[e] = __ballot(v >= 0.5f);
  }
  if (lane < 4) {
    unsigned long long mv = m[0];
    mv = (lane == 1) ? m[1] : mv;
    mv = (lane == 2) ? m[2] : mv;
    mv = (lane == 3) ? m[3] : mv;
    int w = w0 + lane;
    xb2[((size_t)(w >> 1) * Bn + row) * 2 + (w & 1)] = mv;
  }
}

__global__ void k_pack_w(const float* __restrict__ W, uint64_t* __restrict__ wbT) {
  int g = (int)((blockIdx.x * blockDim.x + threadIdx.x) >> 6);
  int lane = (int)(threadIdx.x & 63);
  constexpr int nq = XW >> 2;
  int row = g / nq;
  int q = g - row * nq;
  if (row >= Hn) return;
  int w0 = q << 2;
  unsigned long long m[4];
#pragma unroll
  for (int e = 0; e < 4; ++e) {
    int col = ((w0 + e) << 6) + lane;
    float v = (col < Dn) ? W[(size_t)row * Dn + col] : 0.0f;
    m[e] = __ballot(v >= 0.5f);
  }
  if (lane < 4) {
    unsigned long long mv = m[0];
    mv = (lane == 1) ? m[1] : mv;
    mv = (lane == 2) ? m[2] : mv;
    mv = (lane == 3) ? m[3] : mv;
    wbT[(size_t)(w0 + lane) * Hpad + row] = mv;
  }
}

__global__ void k_transp(const uint64_t* __restrict__ wbT, uint32_t* __restrict__ wt32) {
  int g = (int)((blockIdx.x * blockDim.x + threadIdx.x) >> 6);
  int lane = (int)(threadIdx.x & 63);
  int w = g % XW;
  int jc = g / XW;
  if (jc >= Hpad / 64) return;
  uint64_t word = wbT[(size_t)w * Hpad + jc * 64 + lane];
  uint64_t mym = 0;
#pragma unroll
  for (int e = 0; e < 64; ++e) {
    unsigned long long m = __ballot((word >> e) & 1ull);
    mym = (lane == e) ? m : mym;
  }
  int d = w * 64 + lane;
  wt32[(size_t)(jc * 2) * Dpad + d] = (uint32_t)mym;
  wt32[(size_t)(jc * 2 + 1) * Dpad + d] = (uint32_t)(mym >> 32);
}

__global__ void k_pack_fwT(const float* __restrict__ cw, float* __restrict__ fwT) {
  int idx = blockIdx.x * blockDim.x + threadIdx.x;
  if (idx >= Hn * 64) return;
  int j = idx >> 6, l = idx & 63;
  float v = 0.0f;
  if (l < Ln) {
    float t = 2.0f * cw[(size_t)l * Hn + j];
    v = 1.0f / (1.0f + expf(-t));
  }
  fwT[idx] = v;
}

__global__ void k_zero(float* __restrict__ p, int n) {
  int i = blockIdx.x * blockDim.x + threadIdx.x;
  if (i < n) p[i] = 0.0f;
}

// ---------- MFMA encoder (R12-verified) ----------
// h = xi8 @ wi8^T (exact i32); z = (h + b_enc + act0b >= 1).
// Writes z floats, zb32 ballot bits (bit-dec fallback), zi8 bytes (MFMA dec A).
__global__ __launch_bounds__(256) void k_enc_mfma(
    const uint8_t* __restrict__ A, const uint8_t* __restrict__ B,
    const float* __restrict__ b_enc, const float* __restrict__ act0b,
    float* __restrict__ z_out, uint32_t* __restrict__ zb32,
    uint8_t* __restrict__ zi8) {
  __shared__ uint8_t As[128 * 128];
  __shared__ uint8_t Bs[128 * 128];
  int tid = (int)threadIdx.x;
  int bn = (int)blockIdx.x;
  int bm = (int)blockIdx.y;
  int wv = __builtin_amdgcn_readfirstlane(tid >> 6);
  int lane = tid & 63;
  int wm = wv >> 1, wn = wv & 1;

  v16i acc[2][2];
#pragma unroll
  for (int i = 0; i < 2; ++i)
#pragma unroll
    for (int j = 0; j < 2; ++j) acc[i][j] = (v16i)0;

  int srow = tid >> 3;
  int sq = tid & 7;
  int ldsw = srow * 128 + ((sq ^ (srow & 7)) << 4);
  const uint8_t* ap = A + ((size_t)(bm * 128 + srow)) * Dpad + sq * 16;
  const uint8_t* bp = B + ((size_t)(bn * 128 + srow)) * Dpad + sq * 16;

  int arow = wm * 64 + (lane & 31);
  int brow = wn * 64 + (lane & 31);
  int khalf = lane >> 5;
  int asw = arow & 7;
  int bsw = brow & 7;

#pragma unroll 1
  for (int kt = 0; kt < 40; ++kt) {
    int k0 = kt * 128;
    v4i ra[4], rb[4];
#pragma unroll
    for (int i = 0; i < 4; ++i) {
      ra[i] = *(const v4i*)(ap + k0 + (size_t)i * 32 * Dpad);
      rb[i] = *(const v4i*)(bp + k0 + (size_t)i * 32 * Dpad);
    }
    __syncthreads();
#pragma unroll
    for (int i = 0; i < 4; ++i) {
      *(v4i*)(As + i * 4096 + ldsw) = ra[i];
      *(v4i*)(Bs + i * 4096 + ldsw) = rb[i];
    }
    __syncthreads();
#pragma unroll
    for (int kk = 0; kk < 4; ++kk) {
      int kq = kk * 2 + khalf;
      v4i a0 = *(const v4i*)(As + arow * 128 + ((kq ^ asw) << 4));
      v4i a1 = *(const v4i*)(As + (arow + 32) * 128 + ((kq ^ asw) << 4));
      v4i b0 = *(const v4i*)(Bs + brow * 128 + ((kq ^ bsw) << 4));
      v4i b1 = *(const v4i*)(Bs + (brow + 32) * 128 + ((kq ^ bsw) << 4));
      acc[0][0] = __builtin_amdgcn_mfma_i32_32x32x32_i8(a0, b0, acc[0][0], 0, 0, 0);
      acc[0][1] = __builtin_amdgcn_mfma_i32_32x32x32_i8(a0, b1, acc[0][1], 0, 0, 0);
      acc[1][0] = __builtin_amdgcn_mfma_i32_32x32x32_i8(a1, b0, acc[1][0], 0, 0, 0);
      acc[1][1] = __builtin_amdgcn_mfma_i32_32x32x32_i8(a1, b1, acc[1][1], 0, 0, 0);
    }
  }

  int col0 = bn * 128 + wn * 64 + (lane & 31);
#pragma unroll
  for (int ni = 0; ni < 2; ++ni) {
    int j = col0 + ni * 32;
    int js = (j < Hn) ? j : (Hn - 1);
    float be = b_enc[js];
    float ab = act0b[js];
    bool jv = j < Hn;
    int hw = (bn * 128 + wn * 64 + ni * 32) >> 5;
#pragma unroll
    for (int mi = 0; mi < 2; ++mi) {
      int rbase = bm * 128 + wm * 64 + mi * 32;
#pragma unroll
      for (int r = 0; r < 16; ++r) {
        int rloc = (r & 3) + 8 * (r >> 2) + 4 * (lane >> 5);
        int b = rbase + rloc;
        // exact: integer-valued acc + b_enc, then + act0_bias (reference order)
        float h = ((float)acc[mi][ni][r] + be) + ab;
        bool zb = jv && (h >= 1.0f);
        if (jv) {
          z_out[(size_t)b * Hn + j] = zb ? 1.0f : 0.0f;
          if (zi8) zi8[(size_t)b * Hpad + j] = zb ? 1 : 0;
        }
        unsigned long long m = __ballot(zb);
        if (lane == 0) {
          int blo = rbase + (r & 3) + 8 * (r >> 2);
          zb32[(size_t)hw * Bn + blo] = (uint32_t)m;
          zb32[(size_t)hw * Bn + blo + 4] = (uint32_t)(m >> 32);
        }
      }
    }
  }
}

// ---------- MFMA decoder (same verified structure; K=2048, strides Hpad) ----------
// xd = zi8 @ wtd^T (exact i32); output = (xd + act3b >= 1) written directly.
__global__ __launch_bounds__(256) void k_dec_mfma(
    const uint8_t* __restrict__ A,   // zi8 [4096][2048]
    const uint8_t* __restrict__ B,   // wtd [5120][2048]
    const float* __restrict__ act3b, float* __restrict__ out) {
  __shared__ uint8_t As[128 * 128];
  __shared__ uint8_t Bs[128 * 128];
  int tid = (int)threadIdx.x;
  int bn = (int)blockIdx.x;  // 0..39
  int bm = (int)blockIdx.y;  // 0..31
  int wv = __builtin_amdgcn_readfirstlane(tid >> 6);
  int lane = tid & 63;
  int wm = wv >> 1, wn = wv & 1;

  v16i acc[2][2];
#pragma unroll
  for (int i = 0; i < 2; ++i)
#pragma unroll
    for (int j = 0; j < 2; ++j) acc[i][j] = (v16i)0;

  int srow = tid >> 3;
  int sq = tid & 7;
  int ldsw = srow * 128 + ((sq ^ (srow & 7)) << 4);
  const uint8_t* ap = A + ((size_t)(bm * 128 + srow)) * Hpad + sq * 16;
  const uint8_t* bp = B + ((size_t)(bn * 128 + srow)) * Hpad + sq * 16;

  int arow = wm * 64 + (lane & 31);
  int brow = wn * 64 + (lane & 31);
  int khalf = lane >> 5;
  int asw = arow & 7;
  int bsw = brow & 7;

#pragma unroll 1
  for (int kt = 0; kt < 16; ++kt) {
    int k0 = kt * 128;
    v4i ra[4], rb[4];
#pragma unroll
    for (int i = 0; i < 4; ++i) {
      ra[i] = *(const v4i*)(ap + k0 + (size_t)i * 32 * Hpad);
      rb[i] = *(const v4i*)(bp + k0 + (size_t)i * 32 * Hpad);
    }
    __syncthreads();
#pragma unroll
    for (int i = 0; i < 4; ++i) {
      *(v4i*)(As + i * 4096 + ldsw) = ra[i];
      *(v4i*)(Bs + i * 4096 + ldsw) = rb[i];
    }
    __syncthreads();
#pragma unroll
    for (int kk = 0; kk < 4; ++kk) {
      int kq = kk * 2 + khalf;
      v4i a0 = *(const v4i*)(As + arow * 128 + ((kq ^ asw) << 4));
      v4i a1 = *(const v4i*)(As + (arow + 32) * 128 + ((kq ^ asw) << 4));
      v4i b0 = *(const v4i*)(Bs + brow * 128 + ((kq ^ bsw) << 4));
      v4i b1 = *(const v4i*)(Bs + (brow + 32) * 128 + ((kq ^ bsw) << 4));
      acc[0][0] = __builtin_amdgcn_mfma_i32_32x32x32_i8(a0, b0, acc[0][0], 0, 0, 0);
      acc[0][1] = __builtin_amdgcn_mfma_i32_32x32x32_i8(a0, b1, acc[0][1], 0, 0, 0);
      acc[1][0] = __builtin_amdgcn_mfma_i32_32x32x32_i8(a1, b0, acc[1][0], 0, 0, 0);
      acc[1][1] = __builtin_amdgcn_mfma_i32_32x32x32_i8(a1, b1, acc[1][1], 0, 0, 0);
    }
  }

  int col0 = bn * 128 + wn * 64 + (lane & 31);
#pragma unroll
  for (int ni = 0; ni < 2; ++ni) {
    int d = col0 + ni * 32;
    int ds = (d < Dn) ? d : (Dn - 1);
    float ab = act3b[ds];
    bool dv = d < Dn;
#pragma unroll
    for (int mi = 0; mi < 2; ++mi) {
      int rbase = bm * 128 + wm * 64 + mi * 32;
#pragma unroll
      for (int r = 0; r < 16; ++r) {
        int rloc = (r & 3) + 8 * (r >> 2) + 4 * (lane >> 5);
        int b = rbase + rloc;
        // exact: integer-valued acc + act3_bias (reference order)
        if (dv) out[(size_t)b * Dn + d] = (((float)acc[mi][ni][r] + ab) >= 1.0f) ? 1.0f : 0.0f;
      }
    }
  }
}

// ---------- fallback bit encoder ----------
__global__ __launch_bounds__(256) void k_enc_bit(const uint64_t* __restrict__ xb2,
                                                 const uint64_t* __restrict__ wbT,
                                                 const float* __restrict__ b_enc,
                                                 const float* __restrict__ act0b,
                                                 float* __restrict__ z_out,
                                                 uint8_t* __restrict__ zb8) {
  __shared__ uint64_t wl[XW][8];
  int tid = (int)threadIdx.x;
  int jg = (int)blockIdx.x;
  int j0 = jg << 3;
#pragma unroll
  for (int k = 0; k < 3; ++k) {
    int idx = k * 256 + tid;
    if (idx < XW * 8) {
      int w = idx >> 3, j = idx & 7;
      wl[w][j] = wbT[(size_t)w * Hpad + j0 + j];
    }
  }
  __syncthreads();
  int wv = __builtin_amdgcn_readfirstlane(tid >> 6);
  int lane = tid & 63;
  int bg = (int)blockIdx.y * 4 + wv;
  int b0 = (bg << 8) + lane;
  int acc[4][8] = {};
  const uint64_t* xp = xb2 + 2 * (size_t)b0;
#pragma unroll 1
  for (int w2 = 0; w2 < XW / 2; ++w2) {
    ulong2 xx[4];
#pragma unroll
    for (int i = 0; i < 4; ++i)
      xx[i] = *(const ulong2*)(xp + ((size_t)w2 * Bn + i * 64) * 2);
#pragma unroll
    for (int t2 = 0; t2 < 4; ++t2) {
      ulong2 wa = *(ulong2*)&wl[2 * w2][2 * t2];
      ulong2 wb = *(ulong2*)&wl[2 * w2 + 1][2 * t2];
#pragma unroll
      for (int i = 0; i < 4; ++i) {
        acc[i][2 * t2]     = popc_acc(xx[i].x & wa.x, acc[i][2 * t2]);
        acc[i][2 * t2 + 1] = popc_acc(xx[i].x & wa.y, acc[i][2 * t2 + 1]);
        acc[i][2 * t2]     = popc_acc(xx[i].y & wb.x, acc[i][2 * t2]);
        acc[i][2 * t2 + 1] = popc_acc(xx[i].y & wb.y, acc[i][2 * t2 + 1]);
      }
    }
  }
  float be[8], ab[8];
#pragma unroll
  for (int t = 0; t < 8; ++t) {
    int j = j0 + t;
    int js = (j < Hn) ? j : (Hn - 1);
    be[t] = b_enc[js];
    ab[t] = act0b[js];
  }
#pragma unroll
  for (int i = 0; i < 4; ++i) {
    int b = b0 + i * 64;
    uint32_t zbyte = 0;
    float zf[8];
#pragma unroll
    for (int t = 0; t < 8; ++t) {
      int j = j0 + t;
      float h = ((float)acc[i][t] + be[t]) + ab[t];
      bool zb = (j < Hn) && (h >= 1.0f);
      zbyte |= zb ? (1u << t) : 0u;
      zf[t] = zb ? 1.0f : 0.0f;
    }
    zb8[((size_t)(jg >> 2) * Bn + b) * 4 + (jg & 3)] = (uint8_t)zbyte;
    if (j0 < Hn) {
      float* zp = z_out + (size_t)b * Hn + j0;
      *(float4*)zp = make_float4(zf[0], zf[1], zf[2], zf[3]);
      *(float4*)(zp + 4) = make_float4(zf[4], zf[5], zf[6], zf[7]);
    }
  }
}

// ---------- fallback bit decoder ----------
__global__ __launch_bounds__(256, 6) void k_dec_bit(const uint32_t* __restrict__ zb32,
                                                    const uint32_t* __restrict__ wt32,
                                                    const float* __restrict__ act3b,
                                                    float* __restrict__ out) {
  __shared__ uint32_t tl[64][8];
  int tid = (int)threadIdx.x;
  int dc = (int)blockIdx.x;
  int d0 = dc << 3;
  {
#pragma unroll
    for (int k = 0; k < 2; ++k) {
      int e = k * 256 + tid;
      int hw = e >> 3, dl = e & 7;
      tl[hw][dl] = wt32[(size_t)hw * Dpad + d0 + dl];
    }
  }
  __syncthreads();
  int wv = __builtin_amdgcn_readfirstlane(tid >> 6);
  int lane = tid & 63;
  int bg = (int)blockIdx.y * 4 + wv;
  int b0 = (bg << 8) + lane;
  int acc[4][8] = {};
  const uint32_t* zp = zb32 + b0;
  uint32_t z0, z1, z2, z3, n0, n1, n2, n3;
  uint4 wA, wB, wAn, wBn;
  z0 = zp[0]; z1 = zp[64]; z2 = zp[128]; z3 = zp[192];
  wA = *(const uint4*)&tl[0][0];
  wB = *(const uint4*)&tl[0][4];
#define DEC_MAC()                                          \
  do {                                                     \
    acc[0][0] = __builtin_popcount(z0 & wA.x) + acc[0][0]; \
    acc[0][1] = __builtin_popcount(z0 & wA.y) + acc[0][1]; \
    acc[0][2] = __builtin_popcount(z0 & wA.z) + acc[0][2]; \
    acc[0][3] = __builtin_popcount(z0 & wA.w) + acc[0][3]; \
    acc[0][4] = __builtin_popcount(z0 & wB.x) + acc[0][4]; \
    acc[0][5] = __builtin_popcount(z0 & wB.y) + acc[0][5]; \
    acc[0][6] = __builtin_popcount(z0 & wB.z) + acc[0][6]; \
    acc[0][7] = __builtin_popcount(z0 & wB.w) + acc[0][7]; \
    acc[1][0] = __builtin_popcount(z1 & wA.x) + acc[1][0]; \
    acc[1][1] = __builtin_popcount(z1 & wA.y) + acc[1][1]; \
    acc[1][2] = __builtin_popcount(z1 & wA.z) + acc[1][2]; \
    acc[1][3] = __builtin_popcount(z1 & wA.w) + acc[1][3]; \
    acc[1][4] = __builtin_popcount(z1 & wB.x) + acc[1][4]; \
    acc[1][5] = __builtin_popcount(z1 & wB.y) + acc[1][5]; \
    acc[1][6] = __builtin_popcount(z1 & wB.z) + acc[1][6]; \
    acc[1][7] = __builtin_popcount(z1 & wB.w) + acc[1][7]; \
    acc[2][0] = __builtin_popcount(z2 & wA.x) + acc[2][0]; \
    acc[2][1] = __builtin_popcount(z2 & wA.y) + acc[2][1]; \
    acc[2][2] = __builtin_popcount(z2 & wA.z) + acc[2][2]; \
    acc[2][3] = __builtin_popcount(z2 & wA.w) + acc[2][3]; \
    acc[2][4] = __builtin_popcount(z2 & wB.x) + acc[2][4]; \
    acc[2][5] = __builtin_popcount(z2 & wB.y) + acc[2][5]; \
    acc[2][6] = __builtin_popcount(z2 & wB.z) + acc[2][6]; \
    acc[2][7] = __builtin_popcount(z2 & wB.w) + acc[2][7]; \
    acc[3][0] = __builtin_popcount(z3 & wA.x) + acc[3][0]; \
    acc[3][1] = __builtin_popcount(z3 & wA.y) + acc[3][1]; \
    acc[3][2] = __builtin_popcount(z3 & wA.z) + acc[3][2]; \
    acc[3][3] = __builtin_popcount(z3 & wA.w) + acc[3][3]; \
    acc[3][4] = __builtin_popcount(z3 & wB.x) + acc[3][4]; \
    acc[3][5] = __builtin_popcount(z3 & wB.y) + acc[3][5]; \
    acc[3][6] = __builtin_popcount(z3 & wB.z) + acc[3][6]; \
    acc[3][7] = __builtin_popcount(z3 & wB.w) + acc[3][7]; \
  } while (0)
#pragma unroll 1
  for (int hw = 0; hw < 64; ++hw) {
    int hn = (hw < 63) ? hw + 1 : hw;
    const uint32_t* zq = zp + (size_t)hn * Bn;
    n0 = zq[0]; n1 = zq[64]; n2 = zq[128]; n3 = zq[192];
    wAn = *(const uint4*)&tl[hn][0];
    wBn = *(const uint4*)&tl[hn][4];
    DEC_MAC();
    z0 = n0; z1 = n1; z2 = n2; z3 = n3;
    wA = wAn; wB = wBn;
  }
#undef DEC_MAC
  float ab[8];
#pragma unroll
  for (int t = 0; t < 8; ++t) {
    int d = d0 + t;
    int ds = (d < Dn) ? d : (Dn - 1);
    ab[t] = act3b[ds];
  }
  if (d0 < Dn) {
#pragma unroll
    for (int i = 0; i < 4; ++i) {
      int b = b0 + i * 64;
      float of[8];
#pragma unroll
      for (int t = 0; t < 8; ++t)
        of[t] = (((float)acc[i][t] + ab[t]) >= 1.0f) ? 1.0f : 0.0f;
      float* op = out + (size_t)b * Dn + d0;
      *(float4*)op = make_float4(of[0], of[1], of[2], of[3]);
      *(float4*)(op + 4) = make_float4(of[4], of[5], of[6], of[7]);
    }
  }
}

// ---------- classifier GEMM ----------
// i8-source version: reads zi8 (4x less BW than f32 z).
__global__ __launch_bounds__(256) void k_cls_i8(const uint8_t* __restrict__ zi8,
                                                const float* __restrict__ fwT,
                                                float* __restrict__ cls) {
  __shared__ float zT[64][132];
  __shared__ float fwL[64][64];
  int tid = (int)threadIdx.x;
  int bb0 = (int)blockIdx.x * 128;
  int jsp = (int)blockIdx.y;
  int tx = tid & 15, ty = tid >> 4;
  float acc[8][4] = {};
  for (int tile = 0; tile < 4; ++tile) {
    int jt0 = jsp * 256 + tile * 64;
    __syncthreads();
#pragma unroll
    for (int k = 0; k < 8; ++k) {
      int idx = k * 256 + tid;
      int r = idx >> 4, c4 = idx & 15;
      int j = jt0 + c4 * 4;
      uchar4 v = make_uchar4(0, 0, 0, 0);
      if (j < Hn) v = *(const uchar4*)(zi8 + (size_t)(bb0 + r) * Hpad + j);
      zT[c4 * 4 + 0][r] = (float)v.x;
      zT[c4 * 4 + 1][r] = (float)v.y;
      zT[c4 * 4 + 2][r] = (float)v.z;
      zT[c4 * 4 + 3][r] = (float)v.w;
    }
#pragma unroll
    for (int k = 0; k < 4; ++k) {
      int idx = k * 256 + tid;
      int jj = idx >> 4, c4 = idx & 15;
      int j = jt0 + jj;
      float4 v = make_float4(0.f, 0.f, 0.f, 0.f);
      if (j < Hn) v = *(const float4*)(fwT + (size_t)j * 64 + c4 * 4);
      *(float4*)&fwL[jj][c4 * 4] = v;
    }
    __syncthreads();
#pragma unroll 4
    for (int jj = 0; jj < 64; ++jj) {
      float4 fv = *(float4*)&fwL[jj][tx * 4];
      float4 za = *(float4*)&zT[jj][ty * 8];
      float4 zb = *(float4*)&zT[jj][ty * 8 + 4];
      float zz[8] = {za.x, za.y, za.z, za.w, zb.x, zb.y, zb.z, zb.w};
      float ff[4] = {fv.x, fv.y, fv.z, fv.w};
#pragma unroll
      for (int i = 0; i < 8; ++i)
#pragma unroll
        for (int l = 0; l < 4; ++l) acc[i][l] += zz[i] * ff[l];
    }
  }
#pragma unroll
  for (int i = 0; i < 8; ++i) {
    int b = bb0 + ty * 8 + i;
#pragma unroll
    for (int l = 0; l < 4; ++l) {
      int L = tx * 4 + l;
      if (L < Ln) atomicAdd(&cls[(size_t)b * Ln + L], acc[i][l]);
    }
  }
}

// f32-source version (fallback tiers).
__global__ __launch_bounds__(256) void k_cls_f32(const float* __restrict__ z,
                                                 const float* __restrict__ fwT,
                                                 float* __restrict__ cls) {
  __shared__ float zT[64][132];
  __shared__ float fwL[64][64];
  int tid = (int)threadIdx.x;
  int bb0 = (int)blockIdx.x * 128;
  int jsp = (int)blockIdx.y;
  int tx = tid & 15, ty = tid >> 4;
  float acc[8][4] = {};
  for (int tile = 0; tile < 4; ++tile) {
    int jt0 = jsp * 256 + tile * 64;
    __syncthreads();
#pragma unroll
    for (int k = 0; k < 8; ++k) {
      int idx = k * 256 + tid;
      int r = idx >> 4, c4 = idx & 15;
      int j = jt0 + c4 * 4;
      float4 v = make_float4(0.f, 0.f, 0.f, 0.f);
      if (j < Hn) v = *(const float4*)(z + (size_t)(bb0 + r) * Hn + j);
      zT[c4 * 4 + 0][r] = v.x;
      zT[c4 * 4 + 1][r] = v.y;
      zT[c4 * 4 + 2][r] = v.z;
      zT[c4 * 4 + 3][r] = v.w;
    }
#pragma unroll
    for (int k = 0; k < 4; ++k) {
      int idx = k * 256 + tid;
      int jj = idx >> 4, c4 = idx & 15;
      int j = jt0 + jj;
      float4 v = make_float4(0.f, 0.f, 0.f, 0.f);
      if (j < Hn) v = *(const float4*)(fwT + (size_t)j * 64 + c4 * 4);
      *(float4*)&fwL[jj][c4 * 4] = v;
    }
    __syncthreads();
#pragma unroll 4
    for (int jj = 0; jj < 64; ++jj) {
      float4 fv = *(float4*)&fwL[jj][tx * 4];
      float4 za = *(float4*)&zT[jj][ty * 8];
      float4 zb = *(float4*)&zT[jj][ty * 8 + 4];
      float zz[8] = {za.x, za.y, za.z, za.w, zb.x, zb.y, zb.z, zb.w};
      float ff[4] = {fv.x, fv.y, fv.z, fv.w};
#pragma unroll
      for (int i = 0; i < 8; ++i)
#pragma unroll
        for (int l = 0; l < 4; ++l) acc[i][l] += zz[i] * ff[l];
    }
  }
#pragma unroll
  for (int i = 0; i < 8; ++i) {
    int b = bb0 + ty * 8 + i;
#pragma unroll
    for (int l = 0; l < 4; ++l) {
      int L = tx * 4 + l;
      if (L < Ln) atomicAdd(&cls[(size_t)b * Ln + L], acc[i][l]);
    }
  }
}

extern "C" void kernel_launch(void* const* d_in, const int* in_sizes, int n_in,
                              void* d_out, int out_size, void* d_ws, size_t ws_size,
                              hipStream_t stream) {
  const float* x     = (const float*)d_in[0];
  const float* W     = (const float*)d_in[1];
  const float* b_enc = (const float*)d_in[2];
  const float* act0b = (const float*)d_in[3];
  const float* act3b = (const float*)d_in[4];
  const float* cw    = (const float*)d_in[5];

  float* out0 = (float*)d_out;
  float* cls  = out0 + (size_t)Bn * Dn;
  float* zout = cls + (size_t)Bn * Ln;

  char* p = (char*)d_ws;
  uint32_t* zb32 = (uint32_t*)p; p += (size_t)64 * Bn * 4;   // 1.05 MB
  float*    fwT  = (float*)p;    p += (size_t)Hn * 64 * 4;   // 0.51 MB
  size_t common = (size_t)(p - (char*)d_ws);

  size_t sz_xi8 = (size_t)Bn * Dpad;    // 21.0 MB
  size_t sz_wi8 = (size_t)Hpad * Dpad;  // 10.5 MB
  size_t sz_zi8 = (size_t)Bn * Hpad;    //  8.4 MB
  size_t sz_wtd = (size_t)Dpad * Hpad;  // 10.5 MB
  size_t sz_wbT = (size_t)XW * Hpad * 8;
  size_t sz_wt32 = (size_t)64 * Dpad * 4;
  size_t full_need = common + sz_xi8 + sz_wi8 + sz_zi8 + sz_wtd;      // ~52 MB
  size_t mid_need  = common + sz_wbT + sz_wt32 + sz_xi8 + sz_wi8;     // ~36 MB

  k_pack_fwT<<<(Hn * 64 + 255) / 256, 256, 0, stream>>>(cw, fwT);
  k_zero<<<(Bn * Ln + 255) / 256, 256, 0, stream>>>(cls, Bn * Ln);

  if (ws_size >= full_need) {
    uint8_t* xi8 = (uint8_t*)p;
    uint8_t* wi8 = xi8 + sz_xi8;
    uint8_t* zi8 = wi8 + sz_wi8;
    uint8_t* wtd = zi8 + sz_zi8;
    k_pack_i8<<<(Bn * (Dpad / 4) + 255) / 256, 256, 0, stream>>>(x, xi8, Bn, Bn, Dn);
    dim3 gwd(Dpad / 256, Hpad / 64);  // (20, 32)
    k_pack_w_dual<<<gwd, 256, 0, stream>>>(W, wi8, wtd);
    dim3 ge(Hpad / 128, Bn / 128);    // (16, 32)
    k_enc_mfma<<<ge, 256, 0, stream>>>(xi8, wi8, b_enc, act0b, zout, zb32, zi8);
    dim3 g3(32, 8);
    k_cls_i8<<<g3, 256, 0, stream>>>(zi8, fwT, cls);
    dim3 gd(Dpad / 128, Bn / 128);    // (40, 32)
    k_dec_mfma<<<gd, 256, 0, stream>>>(zi8, wtd, act3b, out0);
  } else if (ws_size >= mid_need) {
    uint64_t* wbT  = (uint64_t*)p;
    uint32_t* wt32 = (uint32_t*)(p + sz_wbT);
    uint8_t*  xi8  = (uint8_t*)(p + sz_wbT + sz_wt32);
    uint8_t*  wi8  = xi8 + sz_xi8;
    {
      long long waves = (long long)Hn * (XW / 4);
      k_pack_w<<<(int)((waves * 64 + 255) / 256), 256, 0, stream>>>(W, wbT);
    }
    {
      long long waves = (long long)(Hpad / 64) * XW;
      k_transp<<<(int)((waves * 64 + 255) / 256), 256, 0, stream>>>(wbT, wt32);
    }
    k_pack_i8<<<(Bn * (Dpad / 4) + 255) / 256, 256, 0, stream>>>(x, xi8, Bn, Bn, Dn);
    k_pack_i8<<<(Hpad * (Dpad / 4) + 255) / 256, 256, 0, stream>>>(W, wi8, Hpad, Hn, Dn);
    dim3 ge(Hpad / 128, Bn / 128);
    k_enc_mfma<<<ge, 256, 0, stream>>>(xi8, wi8, b_enc, act0b, zout, zb32, (uint8_t*)nullptr);
    dim3 g3(32, 8);
    k_cls_f32<<<g3, 256, 0, stream>>>(zout, fwT, cls);
    dim3 g2(640, 4);
    k_dec_bit<<<g2, 256, 0, stream>>>(zb32, wt32, act3b, out0);
  } else {
    uint64_t* wbT  = (uint64_t*)p;
    uint32_t* wt32 = (uint32_t*)(p + sz_wbT);
    uint64_t* xb2  = (uint64_t*)(p + sz_wbT + sz_wt32);
    {
      long long waves = (long long)Hn * (XW / 4);
      k_pack_w<<<(int)((waves * 64 + 255) / 256), 256, 0, stream>>>(W, wbT);
    }
    {
      long long waves = (long long)(Hpad / 64) * XW;
      k_transp<<<(int)((waves * 64 + 255) / 256), 256, 0, stream>>>(wbT, wt32);
    }
    {
      long long waves = (long long)Bn * (XW / 4);
      k_pack_x<<<(int)((waves * 64 + 255) / 256), 256, 0, stream>>>(x, xb2);
    }
    dim3 g1(256, 4);
    k_enc_bit<<<g1, 256, 0, stream>>>(xb2, wbT, b_enc, act0b, zout, (uint8_t*)zb32);
    dim3 g3(32, 8);
    k_cls_f32<<<g3, 256, 0, stream>>>(zout, fwT, cls);
    dim3 g2(640, 4);
    k_dec_bit<<<g2, 256, 0, stream>>>(zb32, wt32, act3b, out0);
  }
}

// Round 14
// 235.874 us; speedup vs baseline: 1.5908x; 1.0098x over previous
//
#include <hip/hip_runtime.h>
#include <stdint.h>

// Problem sizes.
static constexpr int Bn = 4096;
static constexpr int Dn = 5000;
static constexpr int Hn = 2000;
static constexpr int Ln = 50;
static constexpr int XW = 80;      // u64 words covering D (5120 bits)
static constexpr int Hpad = 2048;  // padded H
static constexpr int Dpad = 5120;  // padded D

typedef int v4i __attribute__((ext_vector_type(4)));
typedef int v16i __attribute__((ext_vector_type(16)));

#if defined(__has_builtin)
#if __has_builtin(__builtin_amdgcn_global_load_lds)
#define HAVE_GLOAD_LDS 1
#endif
#endif

#ifdef HAVE_GLOAD_LDS
__device__ __forceinline__ void gload16(const uint8_t* g, uint8_t* l) {
  // async global->LDS, 16B/lane; LDS dest = wave-uniform base + lane*16.
  __builtin_amdgcn_global_load_lds(
      (const __attribute__((address_space(1))) uint32_t*)g,
      (__attribute__((address_space(3))) uint32_t*)l, 16, 0, 0);
}
#endif

__device__ __forceinline__ int popc_acc(uint64_t v, int acc) {
  acc = __builtin_popcount((uint32_t)v) + acc;
  acc = __builtin_popcount((uint32_t)(v >> 32)) + acc;
  return acc;
}

// ---------- packing ----------
__global__ void k_pack_i8(const float* __restrict__ src, uint8_t* __restrict__ dst,
                          int nrows_out, int nrows_valid, int ncols_src) {
  int g = (int)blockIdx.x * 256 + (int)threadIdx.x;
  int row = g / (Dpad / 4);
  int c4 = g - row * (Dpad / 4);
  if (row >= nrows_out) return;
  int col = c4 * 4;
  uchar4 o = make_uchar4(0, 0, 0, 0);
  if (row < nrows_valid && col + 3 < ncols_src) {
    const float4 v = *(const float4*)(src + (size_t)row * ncols_src + col);
    o.x = v.x >= 0.5f; o.y = v.y >= 0.5f; o.z = v.z >= 0.5f; o.w = v.w >= 0.5f;
  }
  *(uchar4*)(dst + (size_t)row * Dpad + col) = o;
}

// One coalesced W pass -> wi8[j][d] (enc B) AND wtd[d][j] (dec B, i8 transposed).
__global__ __launch_bounds__(256) void k_pack_w_dual(const float* __restrict__ W,
                                                     uint8_t* __restrict__ wi8,
                                                     uint8_t* __restrict__ wtd) {
  int d = (int)blockIdx.x * 256 + (int)threadIdx.x;  // 0..5119
  int j0 = (int)blockIdx.y * 64;
  bool dv = d < Dn;
  uint64_t colbits = 0;
  for (int r = 0; r < 64; ++r) {
    int j = j0 + r;
    float v = (j < Hn && dv) ? W[(size_t)j * Dn + d] : 0.0f;
    uint8_t bit = (v >= 0.5f) ? 1 : 0;
    wi8[(size_t)j * Dpad + d] = bit;
    colbits |= ((uint64_t)bit) << r;
  }
  uint8_t* dst = wtd + (size_t)d * Hpad + j0;
#pragma unroll
  for (int q = 0; q < 4; ++q) {
    uint32_t u[4];
#pragma unroll
    for (int s = 0; s < 4; ++s) {
      uint32_t nib = (uint32_t)((colbits >> (q * 16 + s * 4)) & 0xFull);
      u[s] = (nib & 1u) | (((nib >> 1) & 1u) << 8) | (((nib >> 2) & 1u) << 16) |
             (((nib >> 3) & 1u) << 24);
    }
    *(uint4*)(dst + q * 16) = make_uint4(u[0], u[1], u[2], u[3]);
  }
}

// ---------- bit packing (fallback tiers) ----------
__global__ void k_pack_x(const float* __restrict__ x, uint64_t* __restrict__ xb2) {
  int g = (int)((blockIdx.x * blockDim.x + threadIdx.x) >> 6);
  int lane = (int)(threadIdx.x & 63);
  constexpr int nq = XW >> 2;
  int row = g / nq;
  int q = g - row * nq;
  if (row >= Bn) return;
  int w0 = q << 2;
  unsigned long long m[4];
#pragma unroll
  for (int e = 0; e < 4; ++e) {
    int col = ((w0 + e) << 6) + lane;
    float v = (col < Dn) ? x[(size_t)row * Dn + col] : 0.0f;
    m[e] = __ballot(v >= 0.5f);
  }
  if (lane < 4) {
    unsigned long long mv = m[0];
    mv = (lane == 1) ? m[1] : mv;
    mv = (lane == 2) ? m[2] : mv;
    mv = (lane == 3) ? m[3] : mv;
    int w = w0 + lane;
    xb2[((size_t)(w >> 1) * Bn + row) * 2 + (w & 1)] = mv;
  }
}

__global__ void k_pack_w(const float* __restrict__ W, uint64_t* __restrict__ wbT) {
  int g = (int)((blockIdx.x * blockDim.x + threadIdx.x) >> 6);
  int lane = (int)(threadIdx.x & 63);
  constexpr int nq = XW >> 2;
  int row = g / nq;
  int q = g - row * nq;
  if (row >= Hn) return;
  int w0 = q << 2;
  unsigned long long m[4];
#pragma unroll
  for (int e = 0; e < 4; ++e) {
    int col = ((w0 + e) << 6) + lane;
    float v = (col < Dn) ? W[(size_t)row * Dn + col] : 0.0f;
    m[e] = __ballot(v >= 0.5f);
  }
  if (lane < 4) {
    unsigned long long mv = m[0];
    mv = (lane == 1) ? m[1] : mv;
    mv = (lane == 2) ? m[2] : mv;
    mv = (lane == 3) ? m[3] : mv;
    wbT[(size_t)(w0 + lane) * Hpad + row] = mv;
  }
}

__global__ void k_transp(const uint64_t* __restrict__ wbT, uint32_t* __restrict__ wt32) {
  int g = (int)((blockIdx.x * blockDim.x + threadIdx.x) >> 6);
  int lane = (int)(threadIdx.x & 63);
  int w = g % XW;
  int jc = g / XW;
  if (jc >= Hpad / 64) return;
  uint64_t word = wbT[(size_t)w * Hpad + jc * 64 + lane];
  uint64_t mym = 0;
#pragma unroll
  for (int e = 0; e < 64; ++e) {
    unsigned long long m = __ballot((word >> e) & 1ull);
    mym = (lane == e) ? m : mym;
  }
  int d = w * 64 + lane;
  wt32[(size_t)(jc * 2) * Dpad + d] = (uint32_t)mym;
  wt32[(size_t)(jc * 2 + 1) * Dpad + d] = (uint32_t)(mym >> 32);
}

__global__ void k_pack_fwT(const float* __restrict__ cw, float* __restrict__ fwT) {
  int idx = blockIdx.x * blockDim.x + threadIdx.x;
  if (idx >= Hn * 64) return;
  int j = idx >> 6, l = idx & 63;
  float v = 0.0f;
  if (l < Ln) {
    float t = 2.0f * cw[(size_t)l * Hn + j];
    v = 1.0f / (1.0f + expf(-t));
  }
  fwT[idx] = v;
}

__global__ void k_zero(float* __restrict__ p, int n) {
  int i = blockIdx.x * blockDim.x + threadIdx.x;
  if (i < n) p[i] = 0.0f;
}

// ---------- MFMA encoder ----------
// h = xi8 @ wi8^T (exact i32); z = (h + b_enc + act0b >= 1).
// Staging via global_load_lds(16B) with pre-swizzled SOURCE (rule #21): LDS is
// linear per-wave chunks; lane fetches global col (lane&7)^(lane>>3); reads use
// the same XOR -> conflict-free ds_read_b128, no VGPR round-trip.
__global__ __launch_bounds__(256) void k_enc_mfma(
    const uint8_t* __restrict__ A, const uint8_t* __restrict__ B,
    const float* __restrict__ b_enc, const float* __restrict__ act0b,
    float* __restrict__ z_out, uint32_t* __restrict__ zb32,
    uint8_t* __restrict__ zi8) {
  __shared__ uint8_t As[128 * 128];
  __shared__ uint8_t Bs[128 * 128];
  int tid = (int)threadIdx.x;
  int bn = (int)blockIdx.x;
  int bm = (int)blockIdx.y;
  int wv = __builtin_amdgcn_readfirstlane(tid >> 6);
  int lane = tid & 63;
  int wm = wv >> 1, wn = wv & 1;

  v16i acc[2][2];
#pragma unroll
  for (int i = 0; i < 2; ++i)
#pragma unroll
    for (int j = 0; j < 2; ++j) acc[i][j] = (v16i)0;

#ifdef HAVE_GLOAD_LDS
  // per-lane swizzled source offset; row&7 == lane>>3 for all chunks
  int srow8 = lane >> 3;                      // 0..7
  int scol = (((lane & 7) ^ srow8) << 4);     // swizzled 16B col
  const uint8_t* aSrc[4];
  const uint8_t* bSrc[4];
  uint8_t* aDst[4];
  uint8_t* bDst[4];
#pragma unroll
  for (int i = 0; i < 4; ++i) {
    int r = i * 32 + wv * 8 + srow8;
    aSrc[i] = A + (size_t)(bm * 128 + r) * Dpad + scol;
    bSrc[i] = B + (size_t)(bn * 128 + r) * Dpad + scol;
    aDst[i] = As + (i * 32 + wv * 8) * 128;   // wave-uniform linear dest
    bDst[i] = Bs + (i * 32 + wv * 8) * 128;
  }
#else
  int srow = tid >> 3;
  int sq = tid & 7;
  int ldsw = srow * 128 + ((sq ^ (srow & 7)) << 4);
  const uint8_t* ap = A + ((size_t)(bm * 128 + srow)) * Dpad + sq * 16;
  const uint8_t* bp = B + ((size_t)(bn * 128 + srow)) * Dpad + sq * 16;
#endif

  int arow = wm * 64 + (lane & 31);
  int brow = wn * 64 + (lane & 31);
  int khalf = lane >> 5;
  int asw = arow & 7;
  int bsw = brow & 7;

#pragma unroll 1
  for (int kt = 0; kt < 40; ++kt) {
    int k0 = kt * 128;
#ifdef HAVE_GLOAD_LDS
    __syncthreads();  // all waves done reading previous tile
#pragma unroll
    for (int i = 0; i < 4; ++i) {
      gload16(aSrc[i] + k0, aDst[i]);
      gload16(bSrc[i] + k0, bDst[i]);
    }
    __syncthreads();  // vmcnt drained before barrier -> tile visible
#else
    v4i ra[4], rb[4];
#pragma unroll
    for (int i = 0; i < 4; ++i) {
      ra[i] = *(const v4i*)(ap + k0 + (size_t)i * 32 * Dpad);
      rb[i] = *(const v4i*)(bp + k0 + (size_t)i * 32 * Dpad);
    }
    __syncthreads();
#pragma unroll
    for (int i = 0; i < 4; ++i) {
      *(v4i*)(As + i * 4096 + ldsw) = ra[i];
      *(v4i*)(Bs + i * 4096 + ldsw) = rb[i];
    }
    __syncthreads();
#endif
#pragma unroll
    for (int kk = 0; kk < 4; ++kk) {
      int kq = kk * 2 + khalf;
      v4i a0 = *(const v4i*)(As + arow * 128 + ((kq ^ asw) << 4));
      v4i a1 = *(const v4i*)(As + (arow + 32) * 128 + ((kq ^ asw) << 4));
      v4i b0 = *(const v4i*)(Bs + brow * 128 + ((kq ^ bsw) << 4));
      v4i b1 = *(const v4i*)(Bs + (brow + 32) * 128 + ((kq ^ bsw) << 4));
      acc[0][0] = __builtin_amdgcn_mfma_i32_32x32x32_i8(a0, b0, acc[0][0], 0, 0, 0);
      acc[0][1] = __builtin_amdgcn_mfma_i32_32x32x32_i8(a0, b1, acc[0][1], 0, 0, 0);
      acc[1][0] = __builtin_amdgcn_mfma_i32_32x32x32_i8(a1, b0, acc[1][0], 0, 0, 0);
      acc[1][1] = __builtin_amdgcn_mfma_i32_32x32x32_i8(a1, b1, acc[1][1], 0, 0, 0);
    }
  }

  int col0 = bn * 128 + wn * 64 + (lane & 31);
#pragma unroll
  for (int ni = 0; ni < 2; ++ni) {
    int j = col0 + ni * 32;
    int js = (j < Hn) ? j : (Hn - 1);
    float be = b_enc[js];
    float ab = act0b[js];
    bool jv = j < Hn;
    int hw = (bn * 128 + wn * 64 + ni * 32) >> 5;
#pragma unroll
    for (int mi = 0; mi < 2; ++mi) {
      int rbase = bm * 128 + wm * 64 + mi * 32;
#pragma unroll
      for (int r = 0; r < 16; ++r) {
        int rloc = (r & 3) + 8 * (r >> 2) + 4 * (lane >> 5);
        int b = rbase + rloc;
        // exact: integer-valued acc + b_enc, then + act0_bias (reference order)
        float h = ((float)acc[mi][ni][r] + be) + ab;
        bool zb = jv && (h >= 1.0f);
        if (jv) {
          z_out[(size_t)b * Hn + j] = zb ? 1.0f : 0.0f;
          if (zi8) zi8[(size_t)b * Hpad + j] = zb ? 1 : 0;
        }
        if (zb32) {
          unsigned long long m = __ballot(zb);
          if (lane == 0) {
            int blo = rbase + (r & 3) + 8 * (r >> 2);
            zb32[(size_t)hw * Bn + blo] = (uint32_t)m;
            zb32[(size_t)hw * Bn + blo + 4] = (uint32_t)(m >> 32);
          }
        }
      }
    }
  }
}

// ---------- MFMA decoder (same structure; K=2048) ----------
__global__ __launch_bounds__(256) void k_dec_mfma(
    const uint8_t* __restrict__ A,   // zi8 [4096][2048]
    const uint8_t* __restrict__ B,   // wtd [5120][2048]
    const float* __restrict__ act3b, float* __restrict__ out) {
  __shared__ uint8_t As[128 * 128];
  __shared__ uint8_t Bs[128 * 128];
  int tid = (int)threadIdx.x;
  int bn = (int)blockIdx.x;  // 0..39
  int bm = (int)blockIdx.y;  // 0..31
  int wv = __builtin_amdgcn_readfirstlane(tid >> 6);
  int lane = tid & 63;
  int wm = wv >> 1, wn = wv & 1;

  v16i acc[2][2];
#pragma unroll
  for (int i = 0; i < 2; ++i)
#pragma unroll
    for (int j = 0; j < 2; ++j) acc[i][j] = (v16i)0;

#ifdef HAVE_GLOAD_LDS
  int srow8 = lane >> 3;
  int scol = (((lane & 7) ^ srow8) << 4);
  const uint8_t* aSrc[4];
  const uint8_t* bSrc[4];
  uint8_t* aDst[4];
  uint8_t* bDst[4];
#pragma unroll
  for (int i = 0; i < 4; ++i) {
    int r = i * 32 + wv * 8 + srow8;
    aSrc[i] = A + (size_t)(bm * 128 + r) * Hpad + scol;
    bSrc[i] = B + (size_t)(bn * 128 + r) * Hpad + scol;
    aDst[i] = As + (i * 32 + wv * 8) * 128;
    bDst[i] = Bs + (i * 32 + wv * 8) * 128;
  }
#else
  int srow = tid >> 3;
  int sq = tid & 7;
  int ldsw = srow * 128 + ((sq ^ (srow & 7)) << 4);
  const uint8_t* ap = A + ((size_t)(bm * 128 + srow)) * Hpad + sq * 16;
  const uint8_t* bp = B + ((size_t)(bn * 128 + srow)) * Hpad + sq * 16;
#endif

  int arow = wm * 64 + (lane & 31);
  int brow = wn * 64 + (lane & 31);
  int khalf = lane >> 5;
  int asw = arow & 7;
  int bsw = brow & 7;

#pragma unroll 1
  for (int kt = 0; kt < 16; ++kt) {
    int k0 = kt * 128;
#ifdef HAVE_GLOAD_LDS
    __syncthreads();
#pragma unroll
    for (int i = 0; i < 4; ++i) {
      gload16(aSrc[i] + k0, aDst[i]);
      gload16(bSrc[i] + k0, bDst[i]);
    }
    __syncthreads();
#else
    v4i ra[4], rb[4];
#pragma unroll
    for (int i = 0; i < 4; ++i) {
      ra[i] = *(const v4i*)(ap + k0 + (size_t)i * 32 * Hpad);
      rb[i] = *(const v4i*)(bp + k0 + (size_t)i * 32 * Hpad);
    }
    __syncthreads();
#pragma unroll
    for (int i = 0; i < 4; ++i) {
      *(v4i*)(As + i * 4096 + ldsw) = ra[i];
      *(v4i*)(Bs + i * 4096 + ldsw) = rb[i];
    }
    __syncthreads();
#endif
#pragma unroll
    for (int kk = 0; kk < 4; ++kk) {
      int kq = kk * 2 + khalf;
      v4i a0 = *(const v4i*)(As + arow * 128 + ((kq ^ asw) << 4));
      v4i a1 = *(const v4i*)(As + (arow + 32) * 128 + ((kq ^ asw) << 4));
      v4i b0 = *(const v4i*)(Bs + brow * 128 + ((kq ^ bsw) << 4));
      v4i b1 = *(const v4i*)(Bs + (brow + 32) * 128 + ((kq ^ bsw) << 4));
      acc[0][0] = __builtin_amdgcn_mfma_i32_32x32x32_i8(a0, b0, acc[0][0], 0, 0, 0);
      acc[0][1] = __builtin_amdgcn_mfma_i32_32x32x32_i8(a0, b1, acc[0][1], 0, 0, 0);
      acc[1][0] = __builtin_amdgcn_mfma_i32_32x32x32_i8(a1, b0, acc[1][0], 0, 0, 0);
      acc[1][1] = __builtin_amdgcn_mfma_i32_32x32x32_i8(a1, b1, acc[1][1], 0, 0, 0);
    }
  }

  int col0 = bn * 128 + wn * 64 + (lane & 31);
#pragma unroll
  for (int ni = 0; ni < 2; ++ni) {
    int d = col0 + ni * 32;
    int ds = (d < Dn) ? d : (Dn - 1);
    float ab = act3b[ds];
    bool dv = d < Dn;
#pragma unroll
    for (int mi = 0; mi < 2; ++mi) {
      int rbase = bm * 128 + wm * 64 + mi * 32;
#pragma unroll
      for (int r = 0; r < 16; ++r) {
        int rloc = (r & 3) + 8 * (r >> 2) + 4 * (lane >> 5);
        int b = rbase + rloc;
        // exact: integer-valued acc + act3_bias (reference order)
        if (dv) out[(size_t)b * Dn + d] = (((float)acc[mi][ni][r] + ab) >= 1.0f) ? 1.0f : 0.0f;
      }
    }
  }
}

// ---------- fallback bit encoder ----------
__global__ __launch_bounds__(256) void k_enc_bit(const uint64_t* __restrict__ xb2,
                                                 const uint64_t* __restrict__ wbT,
                                                 const float* __restrict__ b_enc,
                                                 const float* __restrict__ act0b,
                                                 float* __restrict__ z_out,
                                                 uint8_t* __restrict__ zb8) {
  __shared__ uint64_t wl[XW][8];
  int tid = (int)threadIdx.x;
  int jg = (int)blockIdx.x;
  int j0 = jg << 3;
#pragma unroll
  for (int k = 0; k < 3; ++k) {
    int idx = k * 256 + tid;
    if (idx < XW * 8) {
      int w = idx >> 3, j = idx & 7;
      wl[w][j] = wbT[(size_t)w * Hpad + j0 + j];
    }
  }
  __syncthreads();
  int wv = __builtin_amdgcn_readfirstlane(tid >> 6);
  int lane = tid & 63;
  int bg = (int)blockIdx.y * 4 + wv;
  int b0 = (bg << 8) + lane;
  int acc[4][8] = {};
  const uint64_t* xp = xb2 + 2 * (size_t)b0;
#pragma unroll 1
  for (int w2 = 0; w2 < XW / 2; ++w2) {
    ulong2 xx[4];
#pragma unroll
    for (int i = 0; i < 4; ++i)
      xx[i] = *(const ulong2*)(xp + ((size_t)w2 * Bn + i * 64) * 2);
#pragma unroll
    for (int t2 = 0; t2 < 4; ++t2) {
      ulong2 wa = *(ulong2*)&wl[2 * w2][2 * t2];
      ulong2 wb = *(ulong2*)&wl[2 * w2 + 1][2 * t2];
#pragma unroll
      for (int i = 0; i < 4; ++i) {
        acc[i][2 * t2]     = popc_acc(xx[i].x & wa.x, acc[i][2 * t2]);
        acc[i][2 * t2 + 1] = popc_acc(xx[i].x & wa.y, acc[i][2 * t2 + 1]);
        acc[i][2 * t2]     = popc_acc(xx[i].y & wb.x, acc[i][2 * t2]);
        acc[i][2 * t2 + 1] = popc_acc(xx[i].y & wb.y, acc[i][2 * t2 + 1]);
      }
    }
  }
  float be[8], ab[8];
#pragma unroll
  for (int t = 0; t < 8; ++t) {
    int j = j0 + t;
    int js = (j < Hn) ? j : (Hn - 1);
    be[t] = b_enc[js];
    ab[t] = act0b[js];
  }
#pragma unroll
  for (int i = 0; i < 4; ++i) {
    int b = b0 + i * 64;
    uint32_t zbyte = 0;
    float zf[8];
#pragma unroll
    for (int t = 0; t < 8; ++t) {
      int j = j0 + t;
      float h = ((float)acc[i][t] + be[t]) + ab[t];
      bool zb = (j < Hn) && (h >= 1.0f);
      zbyte |= zb ? (1u << t) : 0u;
      zf[t] = zb ? 1.0f : 0.0f;
    }
    zb8[((size_t)(jg >> 2) * Bn + b) * 4 + (jg & 3)] = (uint8_t)zbyte;
    if (j0 < Hn) {
      float* zp = z_out + (size_t)b * Hn + j0;
      *(float4*)zp = make_float4(zf[0], zf[1], zf[2], zf[3]);
      *(float4*)(zp + 4) = make_float4(zf[4], zf[5], zf[6], zf[7]);
    }
  }
}

// ---------- fallback bit decoder ----------
__global__ __launch_bounds__(256, 6) void k_dec_bit(const uint32_t* __restrict__ zb32,
                                                    const uint32_t* __restrict__ wt32,
                                                    const float* __restrict__ act3b,
                                                    float* __restrict__ out) {
  __shared__ uint32_t tl[64][8];
  int tid = (int)threadIdx.x;
  int dc = (int)blockIdx.x;
  int d0 = dc << 3;
  {
#pragma unroll
    for (int k = 0; k < 2; ++k) {
      int e = k * 256 + tid;
      int hw = e >> 3, dl = e & 7;
      tl[hw][dl] = wt32[(size_t)hw * Dpad + d0 + dl];
    }
  }
  __syncthreads();
  int wv = __builtin_amdgcn_readfirstlane(tid >> 6);
  int lane = tid & 63;
  int bg = (int)blockIdx.y * 4 + wv;
  int b0 = (bg << 8) + lane;
  int acc[4][8] = {};
  const uint32_t* zp = zb32 + b0;
  uint32_t z0, z1, z2, z3, n0, n1, n2, n3;
  uint4 wA, wB, wAn, wBn;
  z0 = zp[0]; z1 = zp[64]; z2 = zp[128]; z3 = zp[192];
  wA = *(const uint4*)&tl[0][0];
  wB = *(const uint4*)&tl[0][4];
#define DEC_MAC()                                          \
  do {                                                     \
    acc[0][0] = __builtin_popcount(z0 & wA.x) + acc[0][0]; \
    acc[0][1] = __builtin_popcount(z0 & wA.y) + acc[0][1]; \
    acc[0][2] = __builtin_popcount(z0 & wA.z) + acc[0][2]; \
    acc[0][3] = __builtin_popcount(z0 & wA.w) + acc[0][3]; \
    acc[0][4] = __builtin_popcount(z0 & wB.x) + acc[0][4]; \
    acc[0][5] = __builtin_popcount(z0 & wB.y) + acc[0][5]; \
    acc[0][6] = __builtin_popcount(z0 & wB.z) + acc[0][6]; \
    acc[0][7] = __builtin_popcount(z0 & wB.w) + acc[0][7]; \
    acc[1][0] = __builtin_popcount(z1 & wA.x) + acc[1][0]; \
    acc[1][1] = __builtin_popcount(z1 & wA.y) + acc[1][1]; \
    acc[1][2] = __builtin_popcount(z1 & wA.z) + acc[1][2]; \
    acc[1][3] = __builtin_popcount(z1 & wA.w) + acc[1][3]; \
    acc[1][4] = __builtin_popcount(z1 & wB.x) + acc[1][4]; \
    acc[1][5] = __builtin_popcount(z1 & wB.y) + acc[1][5]; \
    acc[1][6] = __builtin_popcount(z1 & wB.z) + acc[1][6]; \
    acc[1][7] = __builtin_popcount(z1 & wB.w) + acc[1][7]; \
    acc[2][0] = __builtin_popcount(z2 & wA.x) + acc[2][0]; \
    acc[2][1] = __builtin_popcount(z2 & wA.y) + acc[2][1]; \
    acc[2][2] = __builtin_popcount(z2 & wA.z) + acc[2][2]; \
    acc[2][3] = __builtin_popcount(z2 & wA.w) + acc[2][3]; \
    acc[2][4] = __builtin_popcount(z2 & wB.x) + acc[2][4]; \
    acc[2][5] = __builtin_popcount(z2 & wB.y) + acc[2][5]; \
    acc[2][6] = __builtin_popcount(z2 & wB.z) + acc[2][6]; \
    acc[2][7] = __builtin_popcount(z2 & wB.w) + acc[2][7]; \
    acc[3][0] = __builtin_popcount(z3 & wA.x) + acc[3][0]; \
    acc[3][1] = __builtin_popcount(z3 & wA.y) + acc[3][1]; \
    acc[3][2] = __builtin_popcount(z3 & wA.z) + acc[3][2]; \
    acc[3][3] = __builtin_popcount(z3 & wA.w) + acc[3][3]; \
    acc[3][4] = __builtin_popcount(z3 & wB.x) + acc[3][4]; \
    acc[3][5] = __builtin_popcount(z3 & wB.y) + acc[3][5]; \
    acc[3][6] = __builtin_popcount(z3 & wB.z) + acc[3][6]; \
    acc[3][7] = __builtin_popcount(z3 & wB.w) + acc[3][7]; \
  } while (0)
#pragma unroll 1
  for (int hw = 0; hw < 64; ++hw) {
    int hn = (hw < 63) ? hw + 1 : hw;
    const uint32_t* zq = zp + (size_t)hn * Bn;
    n0 = zq[0]; n1 = zq[64]; n2 = zq[128]; n3 = zq[192];
    wAn = *(const uint4*)&tl[hn][0];
    wBn = *(const uint4*)&tl[hn][4];
    DEC_MAC();
    z0 = n0; z1 = n1; z2 = n2; z3 = n3;
    wA = wAn; wB = wBn;
  }
#undef DEC_MAC
  float ab[8];
#pragma unroll
  for (int t = 0; t < 8; ++t) {
    int d = d0 + t;
    int ds = (d < Dn) ? d : (Dn - 1);
    ab[t] = act3b[ds];
  }
  if (d0 < Dn) {
#pragma unroll
    for (int i = 0; i < 4; ++i) {
      int b = b0 + i * 64;
      float of[8];
#pragma unroll
      for (int t = 0; t < 8; ++t)
        of[t] = (((float)acc[i][t] + ab[t]) >= 1.0f) ? 1.0f : 0.0f;
      float* op = out + (size_t)b * Dn + d0;
      *(float4*)op = make_float4(of[0], of[1], of[2], of[3]);
      *(float4*)(op + 4) = make_float4(of[4], of[5], of[6], of[7]);
    }
  }
}

// ---------- classifier GEMM ----------
__global__ __launch_bounds__(256) void k_cls_i8(const uint8_t* __restrict__ zi8,
                                                const float* __restrict__ fwT,
                                                float* __restrict__ cls) {
  __shared__ float zT[64][132];
  __shared__ float fwL[64][64];
  int tid = (int)threadIdx.x;
  int bb0 = (int)blockIdx.x * 128;
  int jsp = (int)blockIdx.y;
  int tx = tid & 15, ty = tid >> 4;
  float acc[8][4] = {};
  for (int tile = 0; tile < 4; ++tile) {
    int jt0 = jsp * 256 + tile * 64;
    __syncthreads();
#pragma unroll
    for (int k = 0; k < 8; ++k) {
      int idx = k * 256 + tid;
      int r = idx >> 4, c4 = idx & 15;
      int j = jt0 + c4 * 4;
      uchar4 v = make_uchar4(0, 0, 0, 0);
      if (j < Hn) v = *(const uchar4*)(zi8 + (size_t)(bb0 + r) * Hpad + j);
      zT[c4 * 4 + 0][r] = (float)v.x;
      zT[c4 * 4 + 1][r] = (float)v.y;
      zT[c4 * 4 + 2][r] = (float)v.z;
      zT[c4 * 4 + 3][r] = (float)v.w;
    }
#pragma unroll
    for (int k = 0; k < 4; ++k) {
      int idx = k * 256 + tid;
      int jj = idx >> 4, c4 = idx & 15;
      int j = jt0 + jj;
      float4 v = make_float4(0.f, 0.f, 0.f, 0.f);
      if (j < Hn) v = *(const float4*)(fwT + (size_t)j * 64 + c4 * 4);
      *(float4*)&fwL[jj][c4 * 4] = v;
    }
    __syncthreads();
#pragma unroll 4
    for (int jj = 0; jj < 64; ++jj) {
      float4 fv = *(float4*)&fwL[jj][tx * 4];
      float4 za = *(float4*)&zT[jj][ty * 8];
      float4 zb = *(float4*)&zT[jj][ty * 8 + 4];
      float zz[8] = {za.x, za.y, za.z, za.w, zb.x, zb.y, zb.z, zb.w};
      float ff[4] = {fv.x, fv.y, fv.z, fv.w};
#pragma unroll
      for (int i = 0; i < 8; ++i)
#pragma unroll
        for (int l = 0; l < 4; ++l) acc[i][l] += zz[i] * ff[l];
    }
  }
#pragma unroll
  for (int i = 0; i < 8; ++i) {
    int b = bb0 + ty * 8 + i;
#pragma unroll
    for (int l = 0; l < 4; ++l) {
      int L = tx * 4 + l;
      if (L < Ln) atomicAdd(&cls[(size_t)b * Ln + L], acc[i][l]);
    }
  }
}

__global__ __launch_bounds__(256) void k_cls_f32(const float* __restrict__ z,
                                                 const float* __restrict__ fwT,
                                                 float* __restrict__ cls) {
  __shared__ float zT[64][132];
  __shared__ float fwL[64][64];
  int tid = (int)threadIdx.x;
  int bb0 = (int)blockIdx.x * 128;
  int jsp = (int)blockIdx.y;
  int tx = tid & 15, ty = tid >> 4;
  float acc[8][4] = {};
  for (int tile = 0; tile < 4; ++tile) {
    int jt0 = jsp * 256 + tile * 64;
    __syncthreads();
#pragma unroll
    for (int k = 0; k < 8; ++k) {
      int idx = k * 256 + tid;
      int r = idx >> 4, c4 = idx & 15;
      int j = jt0 + c4 * 4;
      float4 v = make_float4(0.f, 0.f, 0.f, 0.f);
      if (j < Hn) v = *(const float4*)(z + (size_t)(bb0 + r) * Hn + j);
      zT[c4 * 4 + 0][r] = v.x;
      zT[c4 * 4 + 1][r] = v.y;
      zT[c4 * 4 + 2][r] = v.z;
      zT[c4 * 4 + 3][r] = v.w;
    }
#pragma unroll
    for (int k = 0; k < 4; ++k) {
      int idx = k * 256 + tid;
      int jj = idx >> 4, c4 = idx & 15;
      int j = jt0 + jj;
      float4 v = make_float4(0.f, 0.f, 0.f, 0.f);
      if (j < Hn) v = *(const float4*)(fwT + (size_t)j * 64 + c4 * 4);
      *(float4*)&fwL[jj][c4 * 4] = v;
    }
    __syncthreads();
#pragma unroll 4
    for (int jj = 0; jj < 64; ++jj) {
      float4 fv = *(float4*)&fwL[jj][tx * 4];
      float4 za = *(float4*)&zT[jj][ty * 8];
      float4 zb = *(float4*)&zT[jj][ty * 8 + 4];
      float zz[8] = {za.x, za.y, za.z, za.w, zb.x, zb.y, zb.z, zb.w};
      float ff[4] = {fv.x, fv.y, fv.z, fv.w};
#pragma unroll
      for (int i = 0; i < 8; ++i)
#pragma unroll
        for (int l = 0; l < 4; ++l) acc[i][l] += zz[i] * ff[l];
    }
  }
#pragma unroll
  for (int i = 0; i < 8; ++i) {
    int b = bb0 + ty * 8 + i;
#pragma unroll
    for (int l = 0; l < 4; ++l) {
      int L = tx * 4 + l;
      if (L < Ln) atomicAdd(&cls[(size_t)b * Ln + L], acc[i][l]);
    }
  }
}

extern "C" void kernel_launch(void* const* d_in, const int* in_sizes, int n_in,
                              void* d_out, int out_size, void* d_ws, size_t ws_size,
                              hipStream_t stream) {
  const float* x     = (const float*)d_in[0];
  const float* W     = (const float*)d_in[1];
  const float* b_enc = (const float*)d_in[2];
  const float* act0b = (const float*)d_in[3];
  const float* act3b = (const float*)d_in[4];
  const float* cw    = (const float*)d_in[5];

  float* out0 = (float*)d_out;
  float* cls  = out0 + (size_t)Bn * Dn;
  float* zout = cls + (size_t)Bn * Ln;

  char* p = (char*)d_ws;
  uint32_t* zb32 = (uint32_t*)p; p += (size_t)64 * Bn * 4;   // 1.05 MB
  float*    fwT  = (float*)p;    p += (size_t)Hn * 64 * 4;   // 0.51 MB
  size_t common = (size_t)(p - (char*)d_ws);

  size_t sz_xi8 = (size_t)Bn * Dpad;    // 21.0 MB
  size_t sz_wi8 = (size_t)Hpad * Dpad;  // 10.5 MB
  size_t sz_zi8 = (size_t)Bn * Hpad;    //  8.4 MB
  size_t sz_wtd = (size_t)Dpad * Hpad;  // 10.5 MB
  size_t sz_wbT = (size_t)XW * Hpad * 8;
  size_t sz_wt32 = (size_t)64 * Dpad * 4;
  size_t full_need = common + sz_xi8 + sz_wi8 + sz_zi8 + sz_wtd;   // ~52 MB
  size_t mid_need  = common + sz_wbT + sz_wt32 + sz_xi8 + sz_wi8;  // ~36 MB

  k_pack_fwT<<<(Hn * 64 + 255) / 256, 256, 0, stream>>>(cw, fwT);
  k_zero<<<(Bn * Ln + 255) / 256, 256, 0, stream>>>(cls, Bn * Ln);

  if (ws_size >= full_need) {
    uint8_t* xi8 = (uint8_t*)p;
    uint8_t* wi8 = xi8 + sz_xi8;
    uint8_t* zi8 = wi8 + sz_wi8;
    uint8_t* wtd = zi8 + sz_zi8;
    k_pack_i8<<<(Bn * (Dpad / 4) + 255) / 256, 256, 0, stream>>>(x, xi8, Bn, Bn, Dn);
    dim3 gwd(Dpad / 256, Hpad / 64);  // (20, 32)
    k_pack_w_dual<<<gwd, 256, 0, stream>>>(W, wi8, wtd);
    dim3 ge(Hpad / 128, Bn / 128);    // (16, 32)
    k_enc_mfma<<<ge, 256, 0, stream>>>(xi8, wi8, b_enc, act0b, zout,
                                       (uint32_t*)nullptr, zi8);
    dim3 g3(32, 8);
    k_cls_i8<<<g3, 256, 0, stream>>>(zi8, fwT, cls);
    dim3 gd(Dpad / 128, Bn / 128);    // (40, 32)
    k_dec_mfma<<<gd, 256, 0, stream>>>(zi8, wtd, act3b, out0);
  } else if (ws_size >= mid_need) {
    uint64_t* wbT  = (uint64_t*)p;
    uint32_t* wt32 = (uint32_t*)(p + sz_wbT);
    uint8_t*  xi8  = (uint8_t*)(p + sz_wbT + sz_wt32);
    uint8_t*  wi8  = xi8 + sz_xi8;
    {
      long long waves = (long long)Hn * (XW / 4);
      k_pack_w<<<(int)((waves * 64 + 255) / 256), 256, 0, stream>>>(W, wbT);
    }
    {
      long long waves = (long long)(Hpad / 64) * XW;
      k_transp<<<(int)((waves * 64 + 255) / 256), 256, 0, stream>>>(wbT, wt32);
    }
    k_pack_i8<<<(Bn * (Dpad / 4) + 255) / 256, 256, 0, stream>>>(x, xi8, Bn, Bn, Dn);
    k_pack_i8<<<(Hpad * (Dpad / 4) + 255) / 256, 256, 0, stream>>>(W, wi8, Hpad, Hn, Dn);
    dim3 ge(Hpad / 128, Bn / 128);
    k_enc_mfma<<<ge, 256, 0, stream>>>(xi8, wi8, b_enc, act0b, zout, zb32,
                                       (uint8_t*)nullptr);
    dim3 g3(32, 8);
    k_cls_f32<<<g3, 256, 0, stream>>>(zout, fwT, cls);
    dim3 g2(640, 4);
    k_dec_bit<<<g2, 256, 0, stream>>>(zb32, wt32, act3b, out0);
  } else {
    uint64_t* wbT  = (uint64_t*)p;
    uint32_t* wt32 = (uint32_t*)(p + sz_wbT);
    uint64_t* xb2  = (uint64_t*)(p + sz_wbT + sz_wt32);
    {
      long long waves = (long long)Hn * (XW / 4);
      k_pack_w<<<(int)((waves * 64 + 255) / 256), 256, 0, stream>>>(W, wbT);
    }
    {
      long long waves = (long long)(Hpad / 64) * XW;
      k_transp<<<(int)((waves * 64 + 255) / 256), 256, 0, stream>>>(wbT, wt32);
    }
    {
      long long waves = (long long)Bn * (XW / 4);
      k_pack_x<<<(int)((waves * 64 + 255) / 256), 256, 0, stream>>>(x, xb2);
    }
    dim3 g1(256, 4);
    k_enc_bit<<<g1, 256, 0, stream>>>(xb2, wbT, b_enc, act0b, zout, (uint8_t*)zb32);
    dim3 g3(32, 8);
    k_cls_f32<<<g3, 256, 0, stream>>>(zout, fwT, cls);
    dim3 g2(640, 4);
    k_dec_bit<<<g2, 256, 0, stream>>>(zb32, wt32, act3b, out0);
  }
}